// Round 6
// baseline (701.681 us; speedup 1.0000x reference)
//
#include <hip/hip_runtime.h>
#include <cstdint>

// ============================================================================
// Supernetwork: conv-bn-relu-pool x3 backbone -> beam search -> expert dispatch
// All compute in fp32 (bf16 MFMA would flip beam-search top_k orderings).
// Intermediates NHWC. Conv bias omitted (cancelled exactly by BN mean-sub).
// R7: conv1 stats/apply get amdgpu_waves_per_eu(2,2). R6 counters showed
// VGPR_Count still 64 (+~64 AGPR: occupancy capped at 128 regs/wave) and ~3x
// VALU-issue bloat vs hand count -> accumulator still round-trips through
// AGPRs (v_accvgpr_read/write). Pinning 2 waves/EU gives the allocator a
// 256-reg arch budget so y[4][8] + stats live entirely in VGPRs.
// ============================================================================

// ---- ws layout (in floats) ----
static constexpr size_t O_SC    = 0;        // 192: [sc1|sh1|sc2|sh2|sc3|sh3] (64 each stage)
static constexpr size_t O_W1T   = 256;      // 864   w1t[k*32+co], k=ci*9+kh*3+kw
static constexpr size_t O_W2T   = 1152;     // 9216  w2t[k*32+co], k=(kh*3+kw)*32+ci
static constexpr size_t O_W3T   = 10368;    // 9216
static constexpr size_t O_SCORES= 19584;    // 8192
static constexpr size_t O_P0    = 27776;    // 8192 each
static constexpr size_t O_P1    = 35968;
static constexpr size_t O_P2    = 44160;
static constexpr size_t O_OP0   = 52352;    // int32, 8192 each
static constexpr size_t O_OP1   = 60544;
static constexpr size_t O_OP2   = 68736;
static constexpr size_t O_SRC1  = 76928;    // int32
static constexpr size_t O_SRC2  = 85120;
static constexpr size_t O_H0    = 93312;    // 2048*128
static constexpr size_t O_H     = 355456;   // 8192*128 (beam h; reused as stats partials in backbone)
static constexpr size_t O_H2    = 1404032;  // 8192*128
static constexpr size_t O_HIDA  = 2452608;  // 8192*128
static constexpr size_t O_HIDB  = 3501184;  // 8192*128
static constexpr size_t O_S1P   = 4549760;  // 2048*225*32 NHWC
static constexpr size_t O_S2C   = 19295360; // 2048*169*32 NHWC
static constexpr size_t O_S2P   = 30371968; // 2048*36*32  NHWC
static constexpr size_t O_S3C   = 32731264; // 2048*16*32  NHWC
static constexpr size_t O_PART  = O_H;      // per-block stats partials (max 2048*64)
static constexpr size_t O_PART2 = O_H + 131072;  // 64*64 second-level partials
// total 33779840 floats = 135.1 MB

// ---------------------------------------------------------------------------
// K0: transpose conv weights to k-major [k][co] once per call
// ---------------------------------------------------------------------------
__global__ void prep_w(const float* __restrict__ w1, const float* __restrict__ w2,
                       const float* __restrict__ w3, float* __restrict__ w1t,
                       float* __restrict__ w2t, float* __restrict__ w3t) {
    int t = blockIdx.x * 256 + threadIdx.x;
    if (t < 864) {                       // w1 OIHW (32,3,3,3): k = ci*9+tap
        int co = t / 27, k = t % 27;
        w1t[k * 32 + co] = w1[t];
    }
    if (t < 9216) {                      // w2/w3 OIHW (32,32,3,3): k = tap*32+ci
        int co = t / 288, rest = t % 288;
        int ci = rest / 9, tap = rest % 9;
        int k = tap * 32 + ci;
        w2t[k * 32 + co] = w2[t];
        w3t[k * 32 + co] = w3[t];
    }
}

// ---------------------------------------------------------------------------
// reduce_part64: level-1 reduction of part[nblocks][64] -> part2[64][64].
// Block b sums rows i === b (mod 64). 64 blocks x 256 thr (4 row-groups).
// ---------------------------------------------------------------------------
__global__ __launch_bounds__(256) void reduce_part64(
    const float* __restrict__ part, int nblocks, float* __restrict__ part2) {
    __shared__ float red[256];
    const int b = blockIdx.x, t = threadIdx.x;
    const int c = t & 63, grp = t >> 6;
    float s = 0.f;
    for (int i = b + 64 * grp; i < nblocks; i += 256)
        s += part[(size_t)i * 64 + c];
    red[t] = s;
    __syncthreads();
    if (t < 64)
        part2[(size_t)b * 64 + t] =
            red[t] + red[64 + t] + red[128 + t] + red[192 + t];
}

// ---------------------------------------------------------------------------
// finalize_stats: reduce per-block partials [nblocks][64] (sum32|sq32) and
// write sc/sh (64 floats). 1 block, 256 threads. (Now always nblocks=64.)
// ---------------------------------------------------------------------------
__global__ __launch_bounds__(256) void finalize_stats(
    const float* __restrict__ part, int nblocks, float invcount,
    const float* __restrict__ g, const float* __restrict__ be,
    float* __restrict__ scsh) {
    __shared__ float red[256];
    const int t = threadIdx.x;
    const int c = t & 63, grp = t >> 6;
    float s = 0.f;
    for (int i = grp; i < nblocks; i += 4) s += part[(size_t)i * 64 + c];
    red[t] = s;
    __syncthreads();
    if (t < 64) red[t] = red[t] + red[64 + t] + red[128 + t] + red[192 + t];
    __syncthreads();
    if (t < 32) {
        float mean = red[t] * invcount;
        float var = red[32 + t] * invcount - mean * mean;
        float sc = g[t] * rsqrtf(var + 1e-5f);
        scsh[t] = sc;
        scsh[32 + t] = be[t] - mean * sc;
    }
}

// ---------------------------------------------------------------------------
// conv1 shared pieces. img4 LDS layout: [32 rows][32 slots], slot = even cols
// 0..15 (c=0,2,..30), odd cols 16..31 (c=1,3,..31). One float4 = (c0,c1,c2,0).
// CONV1_STAGE: cooperative fill from x NCHW (3,32,32).
// CONV1_PQUAD: compute conv outputs y[4][8] for the 2x2 conv-pixel quad of
// pooled pixel (ph,pw): conv px (2ph+dr, 2pw+dc). 16 b128 reads, 864 fmac.
// All indices compile-time after unroll; weights scalar from wb (uniform).
// ---------------------------------------------------------------------------
#define CONV1_STAGE(img4, xin, t)                                              \
    for (int i = (t); i < 1024; i += 256) {                                    \
        int slot = (i & 1) * 16 + ((i & 31) >> 1);                             \
        img4[(i >> 5) * 32 + slot] =                                           \
            make_float4(xin[i], xin[1024 + i], xin[2048 + i], 0.f);            \
    }

#define CONV1_PQUAD(img4, wb, ph, pw, y)                                       \
    {                                                                          \
        const int rbase_ = (2 * (ph)) * 32 + (pw);                             \
        _Pragma("unroll")                                                      \
        for (int rr = 0; rr < 4; ++rr) {                                       \
            float4 v0_ = img4[rbase_ + rr * 32 + 0];                           \
            float4 v1_ = img4[rbase_ + rr * 32 + 16];                          \
            float4 v2_ = img4[rbase_ + rr * 32 + 1];                           \
            float4 v3_ = img4[rbase_ + rr * 32 + 17];                          \
            float vf_[4][3] = {{v0_.x, v0_.y, v0_.z},                          \
                               {v1_.x, v1_.y, v1_.z},                          \
                               {v2_.x, v2_.y, v2_.z},                          \
                               {v3_.x, v3_.y, v3_.z}};                         \
            _Pragma("unroll")                                                  \
            for (int dr = 0; dr < 2; ++dr) {                                   \
                if (rr - dr < 0 || rr - dr > 2) continue;                      \
                _Pragma("unroll")                                              \
                for (int cc = 0; cc < 4; ++cc) {                               \
                    _Pragma("unroll")                                          \
                    for (int dc = 0; dc < 2; ++dc) {                           \
                        if (cc - dc < 0 || cc - dc > 2) continue;              \
                        const int tap_ = (rr - dr) * 3 + (cc - dc);            \
                        _Pragma("unroll")                                      \
                        for (int ci = 0; ci < 3; ++ci) {                       \
                            const float* w8_ = (wb) + (ci * 9 + tap_) * 32;    \
                            float4 wa_ = *(const float4*)w8_;                  \
                            float4 wq_ = *(const float4*)(w8_ + 4);            \
                            const float s_ = vf_[cc][ci];                      \
                            y[dr * 2 + dc][0] += s_ * wa_.x;                   \
                            y[dr * 2 + dc][1] += s_ * wa_.y;                   \
                            y[dr * 2 + dc][2] += s_ * wa_.z;                   \
                            y[dr * 2 + dc][3] += s_ * wa_.w;                   \
                            y[dr * 2 + dc][4] += s_ * wq_.x;                   \
                            y[dr * 2 + dc][5] += s_ * wq_.y;                   \
                            y[dr * 2 + dc][6] += s_ * wq_.z;                   \
                            y[dr * 2 + dc][7] += s_ * wq_.w;                   \
                        }                                                      \
                    }                                                          \
                }                                                              \
            }                                                                  \
        }                                                                      \
    }

// ---------------------------------------------------------------------------
// K1: conv1 stats pass. 1 img/block, 256 thr = 4 waves (ch groups of 8).
// Lane owns pooled quads pp = lane+64j (pp<225; all 4 conv px valid since
// 30x30 tiles exactly into 15x15 2x2 quads). Writes per-block partials.
// waves_per_eu(2,2): 256-reg arch budget -> no AGPR round-trips.
// ---------------------------------------------------------------------------
__global__ __launch_bounds__(256)
__attribute__((amdgpu_waves_per_eu(2, 2))) void conv1_stats_kernel(
    const float* __restrict__ x, const float* __restrict__ w1t,
    float* __restrict__ part) {
    __shared__ float4 img4[1024];   // 16 KB
    const int n = blockIdx.x, t = threadIdx.x;
    const float* xin = x + (size_t)n * 3072;
    CONV1_STAGE(img4, xin, t)
    const int wv = t >> 6, lane = t & 63;
    const int c0s = __builtin_amdgcn_readfirstlane(wv * 8);
    const float* __restrict__ wb = w1t + c0s;
    __syncthreads();
    float sm[8] = {}, sq[8] = {};
#pragma unroll 1
    for (int j = 0; j < 4; ++j) {
        const int pp = lane + 64 * j;
        const bool pv = pp < 225;
        const int pc = pv ? pp : 0;
        const int ph = pc / 15, pw = pc % 15;
        float y[4][8] = {};
        CONV1_PQUAD(img4, wb, ph, pw, y)
        if (pv) {
#pragma unroll
            for (int q = 0; q < 4; ++q)
#pragma unroll
                for (int cc = 0; cc < 8; ++cc) {
                    float v = y[q][cc];
                    sm[cc] += v; sq[cc] += v * v;
                }
        }
    }
#pragma unroll
    for (int off = 32; off > 0; off >>= 1)
#pragma unroll
        for (int cc = 0; cc < 8; ++cc) {
            sm[cc] += __shfl_down(sm[cc], off);
            sq[cc] += __shfl_down(sq[cc], off);
        }
    if (lane == 0) {
        float* dst = part + (size_t)n * 64;
#pragma unroll
        for (int cc = 0; cc < 8; ++cc) {
            dst[c0s + cc] = sm[cc];
            dst[32 + c0s + cc] = sq[cc];
        }
    }
}

// ---------------------------------------------------------------------------
// K2: conv1 recompute + BN + relu + avgpool2 -> s1_pool NHWC (2048,15,15,32)
// Same quad ownership as stats; pooling is lane-local over the quad.
// waves_per_eu(2,2): see K1.
// ---------------------------------------------------------------------------
__global__ __launch_bounds__(256)
__attribute__((amdgpu_waves_per_eu(2, 2))) void conv1_apply_kernel(
    const float* __restrict__ x, const float* __restrict__ w1t,
    const float* __restrict__ scsh, float* __restrict__ s1p) {
    __shared__ float4 img4[1024];
    const int n = blockIdx.x, t = threadIdx.x;
    const float* xin = x + (size_t)n * 3072;
    CONV1_STAGE(img4, xin, t)
    const int wv = t >> 6, lane = t & 63;
    const int c0s = __builtin_amdgcn_readfirstlane(wv * 8);
    const float* __restrict__ wb = w1t + c0s;
    float scv[8], shv[8];
#pragma unroll
    for (int cc = 0; cc < 8; ++cc) {
        scv[cc] = scsh[c0s + cc];
        shv[cc] = scsh[32 + c0s + cc];
    }
    __syncthreads();
#pragma unroll 1
    for (int j = 0; j < 4; ++j) {
        const int pp = lane + 64 * j;
        const bool pv = pp < 225;
        const int pc = pv ? pp : 0;
        const int ph = pc / 15, pw = pc % 15;
        float y[4][8] = {};
        CONV1_PQUAD(img4, wb, ph, pw, y)
        if (pv) {
            float ov[8];
#pragma unroll
            for (int cc = 0; cc < 8; ++cc) {
                float sc = scv[cc], sh = shv[cc];
                float a0 = fmaxf(y[0][cc] * sc + sh, 0.f);
                float a1 = fmaxf(y[1][cc] * sc + sh, 0.f);
                float a2 = fmaxf(y[2][cc] * sc + sh, 0.f);
                float a3 = fmaxf(y[3][cc] * sc + sh, 0.f);
                ov[cc] = 0.25f * (a0 + a1 + a2 + a3);
            }
            float* dst = s1p + ((size_t)n * 225 + pc) * 32 + c0s;
            *(float4*)dst = make_float4(ov[0], ov[1], ov[2], ov[3]);
            *(float4*)(dst + 4) = make_float4(ov[4], ov[5], ov[6], ov[7]);
        }
    }
}

// ---------------------------------------------------------------------------
// K3: conv2 NHWC (15,15,32)->(13,13,32). 1 img/block, 256 thr = 4 waves
// (ch groups). Lane owns pixels p = lane+64j (p<169). img in LDS as
// [225 px][8 float4-cb] with cb XOR (p&7) swizzle -> conflict-free b128
// reads over ci. Weights scalar via readfirstlane'd c0 (no LDS buffer).
// ---------------------------------------------------------------------------
__global__ __launch_bounds__(256) void conv2_kernel(
    const float* __restrict__ s1p, const float* __restrict__ w2t,
    float* __restrict__ s2c) {
    __shared__ float4 img4[1800];  // 225*8 float4 = 28.8 KB
    const int n = blockIdx.x, t = threadIdx.x;
    const float4* src4 = (const float4*)(s1p + (size_t)n * 7200);
    for (int i = t; i < 1800; i += 256) {
        int p = i >> 3, cb = i & 7;
        img4[(p << 3) + (cb ^ (p & 7))] = src4[i];
    }
    const int wv = t >> 6, lane = t & 63;
    const int c0s = __builtin_amdgcn_readfirstlane(wv * 8);
    const float* __restrict__ wbase = w2t + c0s;
    int pxv[3], in0[3];
    bool val[3];
#pragma unroll
    for (int j = 0; j < 3; ++j) {
        int p = lane + 64 * j;
        val[j] = p < 169;
        int pc = val[j] ? p : 0;
        pxv[j] = pc;
        in0[j] = (pc / 13) * 15 + (pc % 13);
    }
    float y[3][8] = {};
    __syncthreads();
#pragma unroll 1
    for (int tap = 0; tap < 9; ++tap) {
        const int dp = (tap / 3) * 15 + (tap % 3);
        int qb[3], qs[3];
#pragma unroll
        for (int j = 0; j < 3; ++j) {
            int q = in0[j] + dp;
            qb[j] = q << 3; qs[j] = q & 7;
        }
        const float* wk = wbase + tap * 1024;   // (tap*32 + ci)*32
#pragma unroll
        for (int cb = 0; cb < 8; ++cb) {
            float4 v0 = img4[qb[0] + (cb ^ qs[0])];
            float4 v1 = img4[qb[1] + (cb ^ qs[1])];
            float4 v2 = img4[qb[2] + (cb ^ qs[2])];
#pragma unroll
            for (int u = 0; u < 4; ++u) {
                const float* w8 = wk + (cb * 4 + u) * 32;
                float4 wa = *(const float4*)w8;
                float4 wb = *(const float4*)(w8 + 4);
                float wreg[8] = {wa.x, wa.y, wa.z, wa.w, wb.x, wb.y, wb.z, wb.w};
                float sv[3] = {((const float*)&v0)[u], ((const float*)&v1)[u],
                               ((const float*)&v2)[u]};
#pragma unroll
                for (int j = 0; j < 3; ++j)
#pragma unroll
                    for (int cc = 0; cc < 8; ++cc)
                        y[j][cc] += sv[j] * wreg[cc];
            }
        }
    }
#pragma unroll
    for (int j = 0; j < 3; ++j)
        if (val[j]) {
            float* dst = s2c + ((size_t)n * 169 + pxv[j]) * 32 + c0s;
            *(float4*)dst = make_float4(y[j][0], y[j][1], y[j][2], y[j][3]);
            *(float4*)(dst + 4) = make_float4(y[j][4], y[j][5], y[j][6], y[j][7]);
        }
}

// ---------------------------------------------------------------------------
// K6: conv3 NHWC (6,6,32)->(4,4,32). 4 img/block, 256 thr = 4 waves (ch
// groups); lane = (img 2b | px 4b). Same swizzled-b128 + scalar-weight form.
// ---------------------------------------------------------------------------
__global__ __launch_bounds__(256) void conv3_kernel(
    const float* __restrict__ s2p, const float* __restrict__ w3t,
    float* __restrict__ s3c) {
    __shared__ float4 img4[1152];  // 4 img * 36 px * 8 = 18 KB
    const int n0 = blockIdx.x * 4, t = threadIdx.x;
    const float4* src4 = (const float4*)(s2p + (size_t)n0 * 1152);
    for (int i = t; i < 1152; i += 256) {
        int im = i / 288, rem = i - im * 288;
        int p = rem >> 3, cb = rem & 7;
        img4[im * 288 + (p << 3) + (cb ^ (p & 7))] = src4[i];
    }
    const int wv = t >> 6, lane = t & 63;
    const int c0s = __builtin_amdgcn_readfirstlane(wv * 8);
    const float* __restrict__ wbase = w3t + c0s;
    const int im = lane >> 4, p = lane & 15;
    const int in0 = (p >> 2) * 6 + (p & 3);
    float y[8] = {};
    __syncthreads();
#pragma unroll 1
    for (int tap = 0; tap < 9; ++tap) {
        const int q = in0 + (tap / 3) * 6 + (tap % 3);
        const int qb = im * 288 + (q << 3), qs = q & 7;
        const float* wk = wbase + tap * 1024;
#pragma unroll
        for (int cb = 0; cb < 8; ++cb) {
            float4 v = img4[qb + (cb ^ qs)];
#pragma unroll
            for (int u = 0; u < 4; ++u) {
                const float* w8 = wk + (cb * 4 + u) * 32;
                float4 wa = *(const float4*)w8;
                float4 wb = *(const float4*)(w8 + 4);
                float wreg[8] = {wa.x, wa.y, wa.z, wa.w, wb.x, wb.y, wb.z, wb.w};
                float s = ((const float*)&v)[u];
#pragma unroll
                for (int cc = 0; cc < 8; ++cc) y[cc] += s * wreg[cc];
            }
        }
    }
    float* dst = s3c + ((size_t)(n0 + im) * 16 + p) * 32 + c0s;
    *(float4*)dst = make_float4(y[0], y[1], y[2], y[3]);
    *(float4*)(dst + 4) = make_float4(y[4], y[5], y[6], y[7]);
}

// ---------------------------------------------------------------------------
// K4/K7: per-channel sum & sumsq over NHWC buffer (C=32) -> per-block partials
// ---------------------------------------------------------------------------
__global__ void stats_partial(const float* __restrict__ buf, int total,
                              float* __restrict__ part) {
    __shared__ float rs[256], rq[256];
    const int t = threadIdx.x;
    float s = 0.f, q = 0.f;
    for (int i = blockIdx.x * 256 + t; i < total; i += gridDim.x * 256) {
        float v = buf[i];
        s += v; q += v * v;
    }
    rs[t] = s; rq[t] = q;
    __syncthreads();
    for (int off = 128; off >= 32; off >>= 1) {
        if (t < off) { rs[t] += rs[t + off]; rq[t] += rq[t + off]; }
        __syncthreads();
    }
    if (t < 32) {
        part[(size_t)blockIdx.x * 64 + t] = rs[t];
        part[(size_t)blockIdx.x * 64 + 32 + t] = rq[t];
    }
}

// ---------------------------------------------------------------------------
// K5: BN+relu+avgpool2 for stage2: s2_conv (13,13) -> s2_pool (6,6) NHWC
// ---------------------------------------------------------------------------
__global__ void bn_pool2(const float* __restrict__ s2c, const float* __restrict__ scsh,
                         float* __restrict__ s2p) {
    __shared__ float bn[64];
    const int t = threadIdx.x;
    if (t < 64) bn[t] = scsh[t];
    __syncthreads();
    for (int idx = blockIdx.x * blockDim.x + t; idx < 2359296;
         idx += gridDim.x * blockDim.x) {
        const int ci = idx & 31, rest = idx >> 5;
        const int pp = rest % 36, n = rest / 36;
        const int ph = pp / 6, pw = pp % 6;
        const float* b = s2c + ((size_t)n * 169 + (2 * ph) * 13 + 2 * pw) * 32 + ci;
        const float s = bn[ci], h = bn[32 + ci];
        float a0 = fmaxf(b[0] * s + h, 0.f);
        float a1 = fmaxf(b[32] * s + h, 0.f);
        float a2 = fmaxf(b[13 * 32] * s + h, 0.f);
        float a3 = fmaxf(b[14 * 32] * s + h, 0.f);
        s2p[idx] = 0.25f * (a0 + a1 + a2 + a3);
    }
}

// ---------------------------------------------------------------------------
// K8: BN+relu+avgpool2 for stage3 writing h0 in NCHW-flat order h0[n][c*4+h*2+w]
// ---------------------------------------------------------------------------
__global__ void bn_pool3_h0(const float* __restrict__ s3c, const float* __restrict__ scsh,
                            float* __restrict__ h0) {
    __shared__ float bn[64];
    const int t = threadIdx.x;
    if (t < 64) bn[t] = scsh[t];
    __syncthreads();
    const int idx = blockIdx.x * 256 + t;
    if (idx >= 262144) return;
    const int n = idx >> 7, rem = idx & 127;
    const int c = rem >> 2, q = rem & 3, ph = q >> 1, pw = q & 1;
    const float* b = s3c + ((size_t)n * 16 + 2 * ph * 4 + 2 * pw) * 32 + c;
    const float s = bn[c], h = bn[32 + c];
    float a0 = fmaxf(b[0] * s + h, 0.f);
    float a1 = fmaxf(b[32] * s + h, 0.f);
    float a2 = fmaxf(b[128] * s + h, 0.f);
    float a3 = fmaxf(b[160] * s + h, 0.f);
    h0[idx] = 0.25f * (a0 + a1 + a2 + a3);
}

// ---------------------------------------------------------------------------
// K9: beam level 0: logits0 = h0.Who + bho; softmax/logsoftmax; stable sort-4
// one wave per sample
// ---------------------------------------------------------------------------
__global__ void beam0_kernel(const float* __restrict__ h0, const float* __restrict__ Who,
                             const float* __restrict__ bho, float* __restrict__ scores,
                             int* __restrict__ op0, float* __restrict__ p0) {
    const int n = blockIdx.x, lane = threadIdx.x;
    const float* hr = h0 + (size_t)n * 128;
    float pt[4] = {};
    for (int i = lane; i < 128; i += 64) {
        float hv = hr[i];
        pt[0] += hv * Who[i * 4 + 0];
        pt[1] += hv * Who[i * 4 + 1];
        pt[2] += hv * Who[i * 4 + 2];
        pt[3] += hv * Who[i * 4 + 3];
    }
#pragma unroll
    for (int off = 32; off > 0; off >>= 1)
#pragma unroll
        for (int o = 0; o < 4; ++o) pt[o] += __shfl_down(pt[o], off);
    if (lane == 0) {
        float lg[4], e[4], probs[4], logp[4];
#pragma unroll
        for (int o = 0; o < 4; ++o) lg[o] = pt[o] + bho[o];
        float m = fmaxf(fmaxf(lg[0], lg[1]), fmaxf(lg[2], lg[3]));
        float sum = 0.f;
#pragma unroll
        for (int o = 0; o < 4; ++o) { e[o] = expf(lg[o] - m); sum += e[o]; }
        float lse = logf(sum);
#pragma unroll
        for (int o = 0; o < 4; ++o) {
            probs[o] = e[o] / sum;
            logp[o] = lg[o] - m - lse;
        }
        bool used[4] = {false, false, false, false};
        for (int slot = 0; slot < 4; ++slot) {
            int best = 0; float bv = -INFINITY;
            for (int o = 0; o < 4; ++o)
                if (!used[o] && logp[o] > bv) { bv = logp[o]; best = o; }
            used[best] = true;
            scores[n * 4 + slot] = bv;
            op0[n * 4 + slot] = best;
            p0[n * 4 + slot] = probs[best];
        }
    }
}

// ---------------------------------------------------------------------------
// K11/K13: beam level >=1: 16 cand = scores[b]+logp[b][o]; stable top-4
// one wave per sample
// ---------------------------------------------------------------------------
__global__ void beam_level(const float* __restrict__ h, const float* __restrict__ Who,
                           const float* __restrict__ bho, float* __restrict__ scores,
                           int* __restrict__ opL, float* __restrict__ pL,
                           int* __restrict__ srcL) {
    __shared__ float logits[16], cand[16], pr[16];
    const int n = blockIdx.x, l = threadIdx.x;
    const int b = l >> 4, o = (l >> 2) & 3, qt = l & 3;
    const float* hr = h + ((size_t)n * 4 + b) * 128;
    float s = 0.f;
    for (int k = qt * 32; k < qt * 32 + 32; ++k) s += hr[k] * Who[k * 4 + o];
    s += __shfl_xor(s, 1);
    s += __shfl_xor(s, 2);
    if (qt == 0) logits[b * 4 + o] = s + bho[o];
    __syncthreads();
    if (l < 4) {
        float lg[4];
#pragma unroll
        for (int o2 = 0; o2 < 4; ++o2) lg[o2] = logits[l * 4 + o2];
        float m = fmaxf(fmaxf(lg[0], lg[1]), fmaxf(lg[2], lg[3]));
        float e[4], sum = 0.f;
#pragma unroll
        for (int o2 = 0; o2 < 4; ++o2) { e[o2] = expf(lg[o2] - m); sum += e[o2]; }
        float lse = logf(sum);
        float sb = scores[n * 4 + l];
#pragma unroll
        for (int o2 = 0; o2 < 4; ++o2) {
            pr[l * 4 + o2] = e[o2] / sum;
            cand[l * 4 + o2] = sb + (lg[o2] - m - lse);
        }
    }
    __syncthreads();
    if (l == 0) {
        bool used[16];
#pragma unroll
        for (int f = 0; f < 16; ++f) used[f] = false;
        float ns[4], np[4]; int nop[4], nsrc[4];
        for (int slot = 0; slot < 4; ++slot) {
            int best = 0; float bv = -INFINITY;
            for (int f = 0; f < 16; ++f)
                if (!used[f] && cand[f] > bv) { bv = cand[f]; best = f; }
            used[best] = true;
            ns[slot] = bv; nsrc[slot] = best >> 2; nop[slot] = best & 3;
            np[slot] = pr[best];
        }
        for (int slot = 0; slot < 4; ++slot) {
            scores[n * 4 + slot] = ns[slot];
            opL[n * 4 + slot] = nop[slot];
            pL[n * 4 + slot] = np[slot];
            srcL[n * 4 + slot] = nsrc[slot];
        }
    }
}

// ---------------------------------------------------------------------------
// K10/K12: h = tanh(src_row @ W_hh + E_op[op] + b_h). 2 rows x 128 cols/block.
// mode 0: src row = h0[r>>2];  mode 1: src row = in[(r&~3)+srcL[r]]
// ---------------------------------------------------------------------------
__global__ __launch_bounds__(256) void h_update(
    const float* __restrict__ in, int mode, const int* __restrict__ srcL,
    const int* __restrict__ opL, const float* __restrict__ Whh,
    const float* __restrict__ Eop, const float* __restrict__ bh,
    float* __restrict__ out) {
    __shared__ float A[256];
    const int r0 = blockIdx.x * 2, t = threadIdx.x;
    const int row = t >> 7, j = t & 127;
    const int r = r0 + row;
    const float* src;
    if (mode == 0) src = in + (size_t)(r >> 2) * 128;
    else           src = in + (size_t)((r & ~3) + srcL[r]) * 128;
    A[t] = src[j];
    __syncthreads();
    float acc = 0.f;
#pragma unroll 8
    for (int k = 0; k < 128; ++k) acc += A[row * 128 + k] * Whh[k * 128 + j];
    out[(size_t)r * 128 + j] = tanhf(acc + Eop[opL[r] * 128 + j] + bh[j]);
}

// ---------------------------------------------------------------------------
// K14-16: dispatch: per row apply only the SELECTED expert (op<3) or identity.
// out = relu((hid @ exp_w[op] + exp_b[op]) * p)  |  relu(hid * p)
// ---------------------------------------------------------------------------
__global__ __launch_bounds__(256) void dispatch_kernel(
    const float* __restrict__ in, int mode, const int* __restrict__ opL,
    const float* __restrict__ pL, const float* __restrict__ expw,
    const float* __restrict__ expb, float* __restrict__ out) {
    __shared__ float A[256];
    const int r0 = blockIdx.x * 2, t = threadIdx.x;
    const int row = t >> 7, j = t & 127;
    const int r = r0 + row;
    const float* src = (mode == 0) ? in + (size_t)(r >> 2) * 128
                                   : in + (size_t)r * 128;
    A[t] = src[j];
    __syncthreads();
    const int op = opL[r];
    const float p = pL[r];
    float res;
    if (op < 3) {
        const float* Bw = expw + (size_t)op * 16384;
        float acc = 0.f;
#pragma unroll 8
        for (int k = 0; k < 128; ++k) acc += A[row * 128 + k] * Bw[k * 128 + j];
        res = (acc + expb[op * 128 + j]) * p;
    } else {
        res = A[row * 128 + j] * p;
    }
    out[(size_t)r * 128 + j] = fmaxf(res, 0.f);
}

// ---------------------------------------------------------------------------
// K17: final head: out = hid @ out_w + out_b  (8192 x 10)
// ---------------------------------------------------------------------------
__global__ void final_kernel(const float* __restrict__ hid, const float* __restrict__ ow,
                             const float* __restrict__ ob, float* __restrict__ out) {
    const int idx = blockIdx.x * 256 + threadIdx.x;
    if (idx >= 81920) return;
    const int r = idx / 10, o = idx % 10;
    const float* hr = hid + (size_t)r * 128;
    float acc = ob[o];
#pragma unroll 8
    for (int k = 0; k < 128; ++k) acc += hr[k] * ow[k * 10 + o];
    out[idx] = acc;
}

// ===========================================================================
extern "C" void kernel_launch(void* const* d_in, const int* in_sizes, int n_in,
                              void* d_out, int out_size, void* d_ws, size_t ws_size,
                              hipStream_t stream) {
    const float* x    = (const float*)d_in[0];
    const float* cw1  = (const float*)d_in[1];
    const float* g1   = (const float*)d_in[3];
    const float* be1  = (const float*)d_in[4];
    const float* cw2  = (const float*)d_in[5];
    const float* g2   = (const float*)d_in[7];
    const float* be2  = (const float*)d_in[8];
    const float* cw3  = (const float*)d_in[9];
    const float* g3   = (const float*)d_in[11];
    const float* be3  = (const float*)d_in[12];
    const float* Whh  = (const float*)d_in[13];
    const float* bh   = (const float*)d_in[14];
    const float* Eop  = (const float*)d_in[15];
    const float* Who  = (const float*)d_in[16];
    const float* bho  = (const float*)d_in[17];
    const float* expw = (const float*)d_in[18];
    const float* expb = (const float*)d_in[19];
    const float* outw = (const float*)d_in[20];
    const float* outb = (const float*)d_in[21];
    float* ws  = (float*)d_ws;
    float* out = (float*)d_out;

    prep_w<<<36, 256, 0, stream>>>(cw1, cw2, cw3, ws + O_W1T, ws + O_W2T, ws + O_W3T);

    // ---- backbone ----
    conv1_stats_kernel<<<2048, 256, 0, stream>>>(x, ws + O_W1T, ws + O_PART);
    reduce_part64<<<64, 256, 0, stream>>>(ws + O_PART, 2048, ws + O_PART2);
    finalize_stats<<<1, 256, 0, stream>>>(ws + O_PART2, 64, 1.f / 1843200.f,
                                          g1, be1, ws + O_SC);
    conv1_apply_kernel<<<2048, 256, 0, stream>>>(x, ws + O_W1T, ws + O_SC, ws + O_S1P);
    conv2_kernel<<<2048, 256, 0, stream>>>(ws + O_S1P, ws + O_W2T, ws + O_S2C);
    stats_partial<<<1024, 256, 0, stream>>>(ws + O_S2C, 2048 * 169 * 32, ws + O_PART);
    reduce_part64<<<64, 256, 0, stream>>>(ws + O_PART, 1024, ws + O_PART2);
    finalize_stats<<<1, 256, 0, stream>>>(ws + O_PART2, 64, 1.f / 346112.f,
                                          g2, be2, ws + O_SC + 64);
    bn_pool2<<<2048, 256, 0, stream>>>(ws + O_S2C, ws + O_SC + 64, ws + O_S2P);
    conv3_kernel<<<512, 256, 0, stream>>>(ws + O_S2P, ws + O_W3T, ws + O_S3C);
    stats_partial<<<256, 256, 0, stream>>>(ws + O_S3C, 2048 * 16 * 32, ws + O_PART);
    reduce_part64<<<64, 256, 0, stream>>>(ws + O_PART, 256, ws + O_PART2);
    finalize_stats<<<1, 256, 0, stream>>>(ws + O_PART2, 64, 1.f / 32768.f,
                                          g3, be3, ws + O_SC + 128);
    bn_pool3_h0<<<1024, 256, 0, stream>>>(ws + O_S3C, ws + O_SC + 128, ws + O_H0);

    // ---- beam search ----
    beam0_kernel<<<2048, 64, 0, stream>>>(ws + O_H0, Who, bho, ws + O_SCORES,
                                          (int*)(ws + O_OP0), ws + O_P0);
    h_update<<<4096, 256, 0, stream>>>(ws + O_H0, 0, (int*)(ws + O_SRC2),
                                       (int*)(ws + O_OP0), Whh, Eop, bh, ws + O_H);
    beam_level<<<2048, 64, 0, stream>>>(ws + O_H, Who, bho, ws + O_SCORES,
                                        (int*)(ws + O_OP1), ws + O_P1,
                                        (int*)(ws + O_SRC1));
    h_update<<<4096, 256, 0, stream>>>(ws + O_H, 1, (int*)(ws + O_SRC1),
                                       (int*)(ws + O_OP1), Whh, Eop, bh, ws + O_H2);
    beam_level<<<2048, 64, 0, stream>>>(ws + O_H2, Who, bho, ws + O_SCORES,
                                        (int*)(ws + O_OP2), ws + O_P2,
                                        (int*)(ws + O_SRC2));

    // ---- expert dispatch (3 rounds) + head ----
    dispatch_kernel<<<4096, 256, 0, stream>>>(ws + O_H0, 0, (int*)(ws + O_OP0),
                                              ws + O_P0, expw, expb, ws + O_HIDA);
    dispatch_kernel<<<4096, 256, 0, stream>>>(ws + O_HIDA, 1, (int*)(ws + O_OP1),
                                              ws + O_P1, expw, expb, ws + O_HIDB);
    dispatch_kernel<<<4096, 256, 0, stream>>>(ws + O_HIDB, 1, (int*)(ws + O_OP2),
                                              ws + O_P2, expw, expb, ws + O_HIDA);
    final_kernel<<<320, 256, 0, stream>>>(ws + O_HIDA, outw, outb, out);
}

// Round 7
// 499.000 us; speedup vs baseline: 1.4062x; 1.4062x over previous
//
#include <hip/hip_runtime.h>
#include <cstdint>

// ============================================================================
// Supernetwork: conv-bn-relu-pool x3 backbone -> beam search -> expert dispatch
// All compute in fp32 (bf16 MFMA would flip beam-search top_k orderings).
// Intermediates NHWC. Conv bias omitted (cancelled exactly by BN mean-sub).
// R8: (a) revert R7's waves_per_eu(2,2) -- occupancy collapse tripled VALU
// time; back to launch_bounds(256,4) (R6 config). (b) CONV1_PQUAD rewritten
// in the fast conv2 idiom: tap-major STREAMING weights (load 8 weights, burn
// them in 32 fmacs, dead) instead of a 5-deep nest with 108 weight-pairs of
// which 4x are duplicates -- that forced ~216 live values -> reg pathology.
// Per-pixel accumulation order (tap-major, ci-inner) unchanged -> same sums.
// ============================================================================

// ---- ws layout (in floats) ----
static constexpr size_t O_SC    = 0;        // 192: [sc1|sh1|sc2|sh2|sc3|sh3] (64 each stage)
static constexpr size_t O_W1T   = 256;      // 864   w1t[k*32+co], k=ci*9+kh*3+kw
static constexpr size_t O_W2T   = 1152;     // 9216  w2t[k*32+co], k=(kh*3+kw)*32+ci
static constexpr size_t O_W3T   = 10368;    // 9216
static constexpr size_t O_SCORES= 19584;    // 8192
static constexpr size_t O_P0    = 27776;    // 8192 each
static constexpr size_t O_P1    = 35968;
static constexpr size_t O_P2    = 44160;
static constexpr size_t O_OP0   = 52352;    // int32, 8192 each
static constexpr size_t O_OP1   = 60544;
static constexpr size_t O_OP2   = 68736;
static constexpr size_t O_SRC1  = 76928;    // int32
static constexpr size_t O_SRC2  = 85120;
static constexpr size_t O_H0    = 93312;    // 2048*128
static constexpr size_t O_H     = 355456;   // 8192*128 (beam h; reused as stats partials in backbone)
static constexpr size_t O_H2    = 1404032;  // 8192*128
static constexpr size_t O_HIDA  = 2452608;  // 8192*128
static constexpr size_t O_HIDB  = 3501184;  // 8192*128
static constexpr size_t O_S1P   = 4549760;  // 2048*225*32 NHWC
static constexpr size_t O_S2C   = 19295360; // 2048*169*32 NHWC
static constexpr size_t O_S2P   = 30371968; // 2048*36*32  NHWC
static constexpr size_t O_S3C   = 32731264; // 2048*16*32  NHWC
static constexpr size_t O_PART  = O_H;      // per-block stats partials (max 2048*64)
static constexpr size_t O_PART2 = O_H + 131072;  // 64*64 second-level partials
// total 33779840 floats = 135.1 MB

// ---------------------------------------------------------------------------
// K0: transpose conv weights to k-major [k][co] once per call
// ---------------------------------------------------------------------------
__global__ void prep_w(const float* __restrict__ w1, const float* __restrict__ w2,
                       const float* __restrict__ w3, float* __restrict__ w1t,
                       float* __restrict__ w2t, float* __restrict__ w3t) {
    int t = blockIdx.x * 256 + threadIdx.x;
    if (t < 864) {                       // w1 OIHW (32,3,3,3): k = ci*9+tap
        int co = t / 27, k = t % 27;
        w1t[k * 32 + co] = w1[t];
    }
    if (t < 9216) {                      // w2/w3 OIHW (32,32,3,3): k = tap*32+ci
        int co = t / 288, rest = t % 288;
        int ci = rest / 9, tap = rest % 9;
        int k = tap * 32 + ci;
        w2t[k * 32 + co] = w2[t];
        w3t[k * 32 + co] = w3[t];
    }
}

// ---------------------------------------------------------------------------
// reduce_part64: level-1 reduction of part[nblocks][64] -> part2[64][64].
// Block b sums rows i === b (mod 64). 64 blocks x 256 thr (4 row-groups).
// ---------------------------------------------------------------------------
__global__ __launch_bounds__(256) void reduce_part64(
    const float* __restrict__ part, int nblocks, float* __restrict__ part2) {
    __shared__ float red[256];
    const int b = blockIdx.x, t = threadIdx.x;
    const int c = t & 63, grp = t >> 6;
    float s = 0.f;
    for (int i = b + 64 * grp; i < nblocks; i += 256)
        s += part[(size_t)i * 64 + c];
    red[t] = s;
    __syncthreads();
    if (t < 64)
        part2[(size_t)b * 64 + t] =
            red[t] + red[64 + t] + red[128 + t] + red[192 + t];
}

// ---------------------------------------------------------------------------
// finalize_stats: reduce per-block partials [nblocks][64] (sum32|sq32) and
// write sc/sh (64 floats). 1 block, 256 threads. (Now always nblocks=64.)
// ---------------------------------------------------------------------------
__global__ __launch_bounds__(256) void finalize_stats(
    const float* __restrict__ part, int nblocks, float invcount,
    const float* __restrict__ g, const float* __restrict__ be,
    float* __restrict__ scsh) {
    __shared__ float red[256];
    const int t = threadIdx.x;
    const int c = t & 63, grp = t >> 6;
    float s = 0.f;
    for (int i = grp; i < nblocks; i += 4) s += part[(size_t)i * 64 + c];
    red[t] = s;
    __syncthreads();
    if (t < 64) red[t] = red[t] + red[64 + t] + red[128 + t] + red[192 + t];
    __syncthreads();
    if (t < 32) {
        float mean = red[t] * invcount;
        float var = red[32 + t] * invcount - mean * mean;
        float sc = g[t] * rsqrtf(var + 1e-5f);
        scsh[t] = sc;
        scsh[32 + t] = be[t] - mean * sc;
    }
}

// ---------------------------------------------------------------------------
// conv1 shared pieces. img4 LDS layout: [32 rows][32 slots], slot = even cols
// 0..15 (c=0,2,..30), odd cols 16..31 (c=1,3,..31). One float4 = (c0,c1,c2,0).
// CONV1_STAGE: cooperative fill from x NCHW (3,32,32).
// CONV1_PQUAD: conv outputs y[4][8] for the 2x2 conv-px quad of pooled pixel
// (ph,pw). Tap-row major: hoist 8 window float4s (2 rows x cols 2pw..2pw+3:
// slots pw, 16+pw, pw+1, 16+pw+1), then stream (tc,ci): one 8-wide weight
// pair -> 32 fmacs -> dead. 24 LDS b128 + 54 weight loads + 864 fmac/quad.
// Per-pixel accumulation order = tap-major, ci-inner (same as before).
// ---------------------------------------------------------------------------
#define CONV1_STAGE(img4, xin, t)                                              \
    for (int i = (t); i < 1024; i += 256) {                                    \
        int slot = (i & 1) * 16 + ((i & 31) >> 1);                             \
        img4[(i >> 5) * 32 + slot] =                                           \
            make_float4(xin[i], xin[1024 + i], xin[2048 + i], 0.f);            \
    }

__device__ __forceinline__ float f4c(float4 v, int ci) {
    return ci == 0 ? v.x : (ci == 1 ? v.y : v.z);
}

#define CONV1_PQUAD(img4, wb, ph, pw, y)                                       \
    {                                                                          \
        _Pragma("unroll")                                                      \
        for (int tr = 0; tr < 3; ++tr) {                                       \
            const int rb_ = (2 * (ph) + tr) * 32 + (pw);                       \
            float4 a0_[4], a1_[4];                                             \
            a0_[0] = img4[rb_ + 0];  a0_[1] = img4[rb_ + 16];                  \
            a0_[2] = img4[rb_ + 1];  a0_[3] = img4[rb_ + 17];                  \
            a1_[0] = img4[rb_ + 32]; a1_[1] = img4[rb_ + 48];                  \
            a1_[2] = img4[rb_ + 33]; a1_[3] = img4[rb_ + 49];                  \
            _Pragma("unroll")                                                  \
            for (int tc = 0; tc < 3; ++tc) {                                   \
                _Pragma("unroll")                                              \
                for (int ci = 0; ci < 3; ++ci) {                               \
                    const float* w8_ = (wb) + (ci * 9 + tr * 3 + tc) * 32;     \
                    float4 wa_ = *(const float4*)w8_;                          \
                    float4 wq_ = *(const float4*)(w8_ + 4);                    \
                    float wr_[8] = {wa_.x, wa_.y, wa_.z, wa_.w,                \
                                    wq_.x, wq_.y, wq_.z, wq_.w};               \
                    const float s00_ = f4c(a0_[tc], ci);                       \
                    const float s01_ = f4c(a0_[tc + 1], ci);                   \
                    const float s10_ = f4c(a1_[tc], ci);                       \
                    const float s11_ = f4c(a1_[tc + 1], ci);                   \
                    _Pragma("unroll")                                          \
                    for (int cc = 0; cc < 8; ++cc) {                           \
                        y[0][cc] += s00_ * wr_[cc];                            \
                        y[1][cc] += s01_ * wr_[cc];                            \
                        y[2][cc] += s10_ * wr_[cc];                            \
                        y[3][cc] += s11_ * wr_[cc];                            \
                    }                                                          \
                }                                                              \
            }                                                                  \
        }                                                                      \
    }

// ---------------------------------------------------------------------------
// K1: conv1 stats pass. 1 img/block, 256 thr = 4 waves (ch groups of 8).
// Lane owns pooled quads pp = lane+64j (pp<225; all 4 conv px valid since
// 30x30 tiles exactly into 15x15 2x2 quads). Writes per-block partials.
// launch_bounds(256,4): 128-VGPR budget.
// ---------------------------------------------------------------------------
__global__ __launch_bounds__(256, 4) void conv1_stats_kernel(
    const float* __restrict__ x, const float* __restrict__ w1t,
    float* __restrict__ part) {
    __shared__ float4 img4[1024];   // 16 KB
    const int n = blockIdx.x, t = threadIdx.x;
    const float* xin = x + (size_t)n * 3072;
    CONV1_STAGE(img4, xin, t)
    const int wv = t >> 6, lane = t & 63;
    const int c0s = __builtin_amdgcn_readfirstlane(wv * 8);
    const float* __restrict__ wb = w1t + c0s;
    __syncthreads();
    float sm[8] = {}, sq[8] = {};
#pragma unroll 1
    for (int j = 0; j < 4; ++j) {
        const int pp = lane + 64 * j;
        const bool pv = pp < 225;
        const int pc = pv ? pp : 0;
        const int ph = pc / 15, pw = pc % 15;
        float y[4][8] = {};
        CONV1_PQUAD(img4, wb, ph, pw, y)
        if (pv) {
#pragma unroll
            for (int q = 0; q < 4; ++q)
#pragma unroll
                for (int cc = 0; cc < 8; ++cc) {
                    float v = y[q][cc];
                    sm[cc] += v; sq[cc] += v * v;
                }
        }
    }
#pragma unroll
    for (int off = 32; off > 0; off >>= 1)
#pragma unroll
        for (int cc = 0; cc < 8; ++cc) {
            sm[cc] += __shfl_down(sm[cc], off);
            sq[cc] += __shfl_down(sq[cc], off);
        }
    if (lane == 0) {
        float* dst = part + (size_t)n * 64;
#pragma unroll
        for (int cc = 0; cc < 8; ++cc) {
            dst[c0s + cc] = sm[cc];
            dst[32 + c0s + cc] = sq[cc];
        }
    }
}

// ---------------------------------------------------------------------------
// K2: conv1 recompute + BN + relu + avgpool2 -> s1_pool NHWC (2048,15,15,32)
// Same quad ownership as stats; pooling is lane-local over the quad.
// ---------------------------------------------------------------------------
__global__ __launch_bounds__(256, 4) void conv1_apply_kernel(
    const float* __restrict__ x, const float* __restrict__ w1t,
    const float* __restrict__ scsh, float* __restrict__ s1p) {
    __shared__ float4 img4[1024];
    const int n = blockIdx.x, t = threadIdx.x;
    const float* xin = x + (size_t)n * 3072;
    CONV1_STAGE(img4, xin, t)
    const int wv = t >> 6, lane = t & 63;
    const int c0s = __builtin_amdgcn_readfirstlane(wv * 8);
    const float* __restrict__ wb = w1t + c0s;
    float scv[8], shv[8];
#pragma unroll
    for (int cc = 0; cc < 8; ++cc) {
        scv[cc] = scsh[c0s + cc];
        shv[cc] = scsh[32 + c0s + cc];
    }
    __syncthreads();
#pragma unroll 1
    for (int j = 0; j < 4; ++j) {
        const int pp = lane + 64 * j;
        const bool pv = pp < 225;
        const int pc = pv ? pp : 0;
        const int ph = pc / 15, pw = pc % 15;
        float y[4][8] = {};
        CONV1_PQUAD(img4, wb, ph, pw, y)
        if (pv) {
            float ov[8];
#pragma unroll
            for (int cc = 0; cc < 8; ++cc) {
                float sc = scv[cc], sh = shv[cc];
                float a0 = fmaxf(y[0][cc] * sc + sh, 0.f);
                float a1 = fmaxf(y[1][cc] * sc + sh, 0.f);
                float a2 = fmaxf(y[2][cc] * sc + sh, 0.f);
                float a3 = fmaxf(y[3][cc] * sc + sh, 0.f);
                ov[cc] = 0.25f * (a0 + a1 + a2 + a3);
            }
            float* dst = s1p + ((size_t)n * 225 + pc) * 32 + c0s;
            *(float4*)dst = make_float4(ov[0], ov[1], ov[2], ov[3]);
            *(float4*)(dst + 4) = make_float4(ov[4], ov[5], ov[6], ov[7]);
        }
    }
}

// ---------------------------------------------------------------------------
// K3: conv2 NHWC (15,15,32)->(13,13,32). 1 img/block, 256 thr = 4 waves
// (ch groups). Lane owns pixels p = lane+64j (p<169). img in LDS as
// [225 px][8 float4-cb] with cb XOR (p&7) swizzle -> conflict-free b128
// reads over ci. Weights scalar via readfirstlane'd c0 (no LDS buffer).
// ---------------------------------------------------------------------------
__global__ __launch_bounds__(256) void conv2_kernel(
    const float* __restrict__ s1p, const float* __restrict__ w2t,
    float* __restrict__ s2c) {
    __shared__ float4 img4[1800];  // 225*8 float4 = 28.8 KB
    const int n = blockIdx.x, t = threadIdx.x;
    const float4* src4 = (const float4*)(s1p + (size_t)n * 7200);
    for (int i = t; i < 1800; i += 256) {
        int p = i >> 3, cb = i & 7;
        img4[(p << 3) + (cb ^ (p & 7))] = src4[i];
    }
    const int wv = t >> 6, lane = t & 63;
    const int c0s = __builtin_amdgcn_readfirstlane(wv * 8);
    const float* __restrict__ wbase = w2t + c0s;
    int pxv[3], in0[3];
    bool val[3];
#pragma unroll
    for (int j = 0; j < 3; ++j) {
        int p = lane + 64 * j;
        val[j] = p < 169;
        int pc = val[j] ? p : 0;
        pxv[j] = pc;
        in0[j] = (pc / 13) * 15 + (pc % 13);
    }
    float y[3][8] = {};
    __syncthreads();
#pragma unroll 1
    for (int tap = 0; tap < 9; ++tap) {
        const int dp = (tap / 3) * 15 + (tap % 3);
        int qb[3], qs[3];
#pragma unroll
        for (int j = 0; j < 3; ++j) {
            int q = in0[j] + dp;
            qb[j] = q << 3; qs[j] = q & 7;
        }
        const float* wk = wbase + tap * 1024;   // (tap*32 + ci)*32
#pragma unroll
        for (int cb = 0; cb < 8; ++cb) {
            float4 v0 = img4[qb[0] + (cb ^ qs[0])];
            float4 v1 = img4[qb[1] + (cb ^ qs[1])];
            float4 v2 = img4[qb[2] + (cb ^ qs[2])];
#pragma unroll
            for (int u = 0; u < 4; ++u) {
                const float* w8 = wk + (cb * 4 + u) * 32;
                float4 wa = *(const float4*)w8;
                float4 wb = *(const float4*)(w8 + 4);
                float wreg[8] = {wa.x, wa.y, wa.z, wa.w, wb.x, wb.y, wb.z, wb.w};
                float sv[3] = {((const float*)&v0)[u], ((const float*)&v1)[u],
                               ((const float*)&v2)[u]};
#pragma unroll
                for (int j = 0; j < 3; ++j)
#pragma unroll
                    for (int cc = 0; cc < 8; ++cc)
                        y[j][cc] += sv[j] * wreg[cc];
            }
        }
    }
#pragma unroll
    for (int j = 0; j < 3; ++j)
        if (val[j]) {
            float* dst = s2c + ((size_t)n * 169 + pxv[j]) * 32 + c0s;
            *(float4*)dst = make_float4(y[j][0], y[j][1], y[j][2], y[j][3]);
            *(float4*)(dst + 4) = make_float4(y[j][4], y[j][5], y[j][6], y[j][7]);
        }
}

// ---------------------------------------------------------------------------
// K6: conv3 NHWC (6,6,32)->(4,4,32). 4 img/block, 256 thr = 4 waves (ch
// groups); lane = (img 2b | px 4b). Same swizzled-b128 + scalar-weight form.
// ---------------------------------------------------------------------------
__global__ __launch_bounds__(256) void conv3_kernel(
    const float* __restrict__ s2p, const float* __restrict__ w3t,
    float* __restrict__ s3c) {
    __shared__ float4 img4[1152];  // 4 img * 36 px * 8 = 18 KB
    const int n0 = blockIdx.x * 4, t = threadIdx.x;
    const float4* src4 = (const float4*)(s2p + (size_t)n0 * 1152);
    for (int i = t; i < 1152; i += 256) {
        int im = i / 288, rem = i - im * 288;
        int p = rem >> 3, cb = rem & 7;
        img4[im * 288 + (p << 3) + (cb ^ (p & 7))] = src4[i];
    }
    const int wv = t >> 6, lane = t & 63;
    const int c0s = __builtin_amdgcn_readfirstlane(wv * 8);
    const float* __restrict__ wbase = w3t + c0s;
    const int im = lane >> 4, p = lane & 15;
    const int in0 = (p >> 2) * 6 + (p & 3);
    float y[8] = {};
    __syncthreads();
#pragma unroll 1
    for (int tap = 0; tap < 9; ++tap) {
        const int q = in0 + (tap / 3) * 6 + (tap % 3);
        const int qb = im * 288 + (q << 3), qs = q & 7;
        const float* wk = wbase + tap * 1024;
#pragma unroll
        for (int cb = 0; cb < 8; ++cb) {
            float4 v = img4[qb + (cb ^ qs)];
#pragma unroll
            for (int u = 0; u < 4; ++u) {
                const float* w8 = wk + (cb * 4 + u) * 32;
                float4 wa = *(const float4*)w8;
                float4 wb = *(const float4*)(w8 + 4);
                float wreg[8] = {wa.x, wa.y, wa.z, wa.w, wb.x, wb.y, wb.z, wb.w};
                float s = ((const float*)&v)[u];
#pragma unroll
                for (int cc = 0; cc < 8; ++cc) y[cc] += s * wreg[cc];
            }
        }
    }
    float* dst = s3c + ((size_t)(n0 + im) * 16 + p) * 32 + c0s;
    *(float4*)dst = make_float4(y[0], y[1], y[2], y[3]);
    *(float4*)(dst + 4) = make_float4(y[4], y[5], y[6], y[7]);
}

// ---------------------------------------------------------------------------
// K4/K7: per-channel sum & sumsq over NHWC buffer (C=32) -> per-block partials
// ---------------------------------------------------------------------------
__global__ void stats_partial(const float* __restrict__ buf, int total,
                              float* __restrict__ part) {
    __shared__ float rs[256], rq[256];
    const int t = threadIdx.x;
    float s = 0.f, q = 0.f;
    for (int i = blockIdx.x * 256 + t; i < total; i += gridDim.x * 256) {
        float v = buf[i];
        s += v; q += v * v;
    }
    rs[t] = s; rq[t] = q;
    __syncthreads();
    for (int off = 128; off >= 32; off >>= 1) {
        if (t < off) { rs[t] += rs[t + off]; rq[t] += rq[t + off]; }
        __syncthreads();
    }
    if (t < 32) {
        part[(size_t)blockIdx.x * 64 + t] = rs[t];
        part[(size_t)blockIdx.x * 64 + 32 + t] = rq[t];
    }
}

// ---------------------------------------------------------------------------
// K5: BN+relu+avgpool2 for stage2: s2_conv (13,13) -> s2_pool (6,6) NHWC
// ---------------------------------------------------------------------------
__global__ void bn_pool2(const float* __restrict__ s2c, const float* __restrict__ scsh,
                         float* __restrict__ s2p) {
    __shared__ float bn[64];
    const int t = threadIdx.x;
    if (t < 64) bn[t] = scsh[t];
    __syncthreads();
    for (int idx = blockIdx.x * blockDim.x + t; idx < 2359296;
         idx += gridDim.x * blockDim.x) {
        const int ci = idx & 31, rest = idx >> 5;
        const int pp = rest % 36, n = rest / 36;
        const int ph = pp / 6, pw = pp % 6;
        const float* b = s2c + ((size_t)n * 169 + (2 * ph) * 13 + 2 * pw) * 32 + ci;
        const float s = bn[ci], h = bn[32 + ci];
        float a0 = fmaxf(b[0] * s + h, 0.f);
        float a1 = fmaxf(b[32] * s + h, 0.f);
        float a2 = fmaxf(b[13 * 32] * s + h, 0.f);
        float a3 = fmaxf(b[14 * 32] * s + h, 0.f);
        s2p[idx] = 0.25f * (a0 + a1 + a2 + a3);
    }
}

// ---------------------------------------------------------------------------
// K8: BN+relu+avgpool2 for stage3 writing h0 in NCHW-flat order h0[n][c*4+h*2+w]
// ---------------------------------------------------------------------------
__global__ void bn_pool3_h0(const float* __restrict__ s3c, const float* __restrict__ scsh,
                            float* __restrict__ h0) {
    __shared__ float bn[64];
    const int t = threadIdx.x;
    if (t < 64) bn[t] = scsh[t];
    __syncthreads();
    const int idx = blockIdx.x * 256 + t;
    if (idx >= 262144) return;
    const int n = idx >> 7, rem = idx & 127;
    const int c = rem >> 2, q = rem & 3, ph = q >> 1, pw = q & 1;
    const float* b = s3c + ((size_t)n * 16 + 2 * ph * 4 + 2 * pw) * 32 + c;
    const float s = bn[c], h = bn[32 + c];
    float a0 = fmaxf(b[0] * s + h, 0.f);
    float a1 = fmaxf(b[32] * s + h, 0.f);
    float a2 = fmaxf(b[128] * s + h, 0.f);
    float a3 = fmaxf(b[160] * s + h, 0.f);
    h0[idx] = 0.25f * (a0 + a1 + a2 + a3);
}

// ---------------------------------------------------------------------------
// K9: beam level 0: logits0 = h0.Who + bho; softmax/logsoftmax; stable sort-4
// one wave per sample
// ---------------------------------------------------------------------------
__global__ void beam0_kernel(const float* __restrict__ h0, const float* __restrict__ Who,
                             const float* __restrict__ bho, float* __restrict__ scores,
                             int* __restrict__ op0, float* __restrict__ p0) {
    const int n = blockIdx.x, lane = threadIdx.x;
    const float* hr = h0 + (size_t)n * 128;
    float pt[4] = {};
    for (int i = lane; i < 128; i += 64) {
        float hv = hr[i];
        pt[0] += hv * Who[i * 4 + 0];
        pt[1] += hv * Who[i * 4 + 1];
        pt[2] += hv * Who[i * 4 + 2];
        pt[3] += hv * Who[i * 4 + 3];
    }
#pragma unroll
    for (int off = 32; off > 0; off >>= 1)
#pragma unroll
        for (int o = 0; o < 4; ++o) pt[o] += __shfl_down(pt[o], off);
    if (lane == 0) {
        float lg[4], e[4], probs[4], logp[4];
#pragma unroll
        for (int o = 0; o < 4; ++o) lg[o] = pt[o] + bho[o];
        float m = fmaxf(fmaxf(lg[0], lg[1]), fmaxf(lg[2], lg[3]));
        float sum = 0.f;
#pragma unroll
        for (int o = 0; o < 4; ++o) { e[o] = expf(lg[o] - m); sum += e[o]; }
        float lse = logf(sum);
#pragma unroll
        for (int o = 0; o < 4; ++o) {
            probs[o] = e[o] / sum;
            logp[o] = lg[o] - m - lse;
        }
        bool used[4] = {false, false, false, false};
        for (int slot = 0; slot < 4; ++slot) {
            int best = 0; float bv = -INFINITY;
            for (int o = 0; o < 4; ++o)
                if (!used[o] && logp[o] > bv) { bv = logp[o]; best = o; }
            used[best] = true;
            scores[n * 4 + slot] = bv;
            op0[n * 4 + slot] = best;
            p0[n * 4 + slot] = probs[best];
        }
    }
}

// ---------------------------------------------------------------------------
// K11/K13: beam level >=1: 16 cand = scores[b]+logp[b][o]; stable top-4
// one wave per sample
// ---------------------------------------------------------------------------
__global__ void beam_level(const float* __restrict__ h, const float* __restrict__ Who,
                           const float* __restrict__ bho, float* __restrict__ scores,
                           int* __restrict__ opL, float* __restrict__ pL,
                           int* __restrict__ srcL) {
    __shared__ float logits[16], cand[16], pr[16];
    const int n = blockIdx.x, l = threadIdx.x;
    const int b = l >> 4, o = (l >> 2) & 3, qt = l & 3;
    const float* hr = h + ((size_t)n * 4 + b) * 128;
    float s = 0.f;
    for (int k = qt * 32; k < qt * 32 + 32; ++k) s += hr[k] * Who[k * 4 + o];
    s += __shfl_xor(s, 1);
    s += __shfl_xor(s, 2);
    if (qt == 0) logits[b * 4 + o] = s + bho[o];
    __syncthreads();
    if (l < 4) {
        float lg[4];
#pragma unroll
        for (int o2 = 0; o2 < 4; ++o2) lg[o2] = logits[l * 4 + o2];
        float m = fmaxf(fmaxf(lg[0], lg[1]), fmaxf(lg[2], lg[3]));
        float e[4], sum = 0.f;
#pragma unroll
        for (int o2 = 0; o2 < 4; ++o2) { e[o2] = expf(lg[o2] - m); sum += e[o2]; }
        float lse = logf(sum);
        float sb = scores[n * 4 + l];
#pragma unroll
        for (int o2 = 0; o2 < 4; ++o2) {
            pr[l * 4 + o2] = e[o2] / sum;
            cand[l * 4 + o2] = sb + (lg[o2] - m - lse);
        }
    }
    __syncthreads();
    if (l == 0) {
        bool used[16];
#pragma unroll
        for (int f = 0; f < 16; ++f) used[f] = false;
        float ns[4], np[4]; int nop[4], nsrc[4];
        for (int slot = 0; slot < 4; ++slot) {
            int best = 0; float bv = -INFINITY;
            for (int f = 0; f < 16; ++f)
                if (!used[f] && cand[f] > bv) { bv = cand[f]; best = f; }
            used[best] = true;
            ns[slot] = bv; nsrc[slot] = best >> 2; nop[slot] = best & 3;
            np[slot] = pr[best];
        }
        for (int slot = 0; slot < 4; ++slot) {
            scores[n * 4 + slot] = ns[slot];
            opL[n * 4 + slot] = nop[slot];
            pL[n * 4 + slot] = np[slot];
            srcL[n * 4 + slot] = nsrc[slot];
        }
    }
}

// ---------------------------------------------------------------------------
// K10/K12: h = tanh(src_row @ W_hh + E_op[op] + b_h). 2 rows x 128 cols/block.
// mode 0: src row = h0[r>>2];  mode 1: src row = in[(r&~3)+srcL[r]]
// ---------------------------------------------------------------------------
__global__ __launch_bounds__(256) void h_update(
    const float* __restrict__ in, int mode, const int* __restrict__ srcL,
    const int* __restrict__ opL, const float* __restrict__ Whh,
    const float* __restrict__ Eop, const float* __restrict__ bh,
    float* __restrict__ out) {
    __shared__ float A[256];
    const int r0 = blockIdx.x * 2, t = threadIdx.x;
    const int row = t >> 7, j = t & 127;
    const int r = r0 + row;
    const float* src;
    if (mode == 0) src = in + (size_t)(r >> 2) * 128;
    else           src = in + (size_t)((r & ~3) + srcL[r]) * 128;
    A[t] = src[j];
    __syncthreads();
    float acc = 0.f;
#pragma unroll 8
    for (int k = 0; k < 128; ++k) acc += A[row * 128 + k] * Whh[k * 128 + j];
    out[(size_t)r * 128 + j] = tanhf(acc + Eop[opL[r] * 128 + j] + bh[j]);
}

// ---------------------------------------------------------------------------
// K14-16: dispatch: per row apply only the SELECTED expert (op<3) or identity.
// out = relu((hid @ exp_w[op] + exp_b[op]) * p)  |  relu(hid * p)
// ---------------------------------------------------------------------------
__global__ __launch_bounds__(256) void dispatch_kernel(
    const float* __restrict__ in, int mode, const int* __restrict__ opL,
    const float* __restrict__ pL, const float* __restrict__ expw,
    const float* __restrict__ expb, float* __restrict__ out) {
    __shared__ float A[256];
    const int r0 = blockIdx.x * 2, t = threadIdx.x;
    const int row = t >> 7, j = t & 127;
    const int r = r0 + row;
    const float* src = (mode == 0) ? in + (size_t)(r >> 2) * 128
                                   : in + (size_t)r * 128;
    A[t] = src[j];
    __syncthreads();
    const int op = opL[r];
    const float p = pL[r];
    float res;
    if (op < 3) {
        const float* Bw = expw + (size_t)op * 16384;
        float acc = 0.f;
#pragma unroll 8
        for (int k = 0; k < 128; ++k) acc += A[row * 128 + k] * Bw[k * 128 + j];
        res = (acc + expb[op * 128 + j]) * p;
    } else {
        res = A[row * 128 + j] * p;
    }
    out[(size_t)r * 128 + j] = fmaxf(res, 0.f);
}

// ---------------------------------------------------------------------------
// K17: final head: out = hid @ out_w + out_b  (8192 x 10)
// ---------------------------------------------------------------------------
__global__ void final_kernel(const float* __restrict__ hid, const float* __restrict__ ow,
                             const float* __restrict__ ob, float* __restrict__ out) {
    const int idx = blockIdx.x * 256 + threadIdx.x;
    if (idx >= 81920) return;
    const int r = idx / 10, o = idx % 10;
    const float* hr = hid + (size_t)r * 128;
    float acc = ob[o];
#pragma unroll 8
    for (int k = 0; k < 128; ++k) acc += hr[k] * ow[k * 10 + o];
    out[idx] = acc;
}

// ===========================================================================
extern "C" void kernel_launch(void* const* d_in, const int* in_sizes, int n_in,
                              void* d_out, int out_size, void* d_ws, size_t ws_size,
                              hipStream_t stream) {
    const float* x    = (const float*)d_in[0];
    const float* cw1  = (const float*)d_in[1];
    const float* g1   = (const float*)d_in[3];
    const float* be1  = (const float*)d_in[4];
    const float* cw2  = (const float*)d_in[5];
    const float* g2   = (const float*)d_in[7];
    const float* be2  = (const float*)d_in[8];
    const float* cw3  = (const float*)d_in[9];
    const float* g3   = (const float*)d_in[11];
    const float* be3  = (const float*)d_in[12];
    const float* Whh  = (const float*)d_in[13];
    const float* bh   = (const float*)d_in[14];
    const float* Eop  = (const float*)d_in[15];
    const float* Who  = (const float*)d_in[16];
    const float* bho  = (const float*)d_in[17];
    const float* expw = (const float*)d_in[18];
    const float* expb = (const float*)d_in[19];
    const float* outw = (const float*)d_in[20];
    const float* outb = (const float*)d_in[21];
    float* ws  = (float*)d_ws;
    float* out = (float*)d_out;

    prep_w<<<36, 256, 0, stream>>>(cw1, cw2, cw3, ws + O_W1T, ws + O_W2T, ws + O_W3T);

    // ---- backbone ----
    conv1_stats_kernel<<<2048, 256, 0, stream>>>(x, ws + O_W1T, ws + O_PART);
    reduce_part64<<<64, 256, 0, stream>>>(ws + O_PART, 2048, ws + O_PART2);
    finalize_stats<<<1, 256, 0, stream>>>(ws + O_PART2, 64, 1.f / 1843200.f,
                                          g1, be1, ws + O_SC);
    conv1_apply_kernel<<<2048, 256, 0, stream>>>(x, ws + O_W1T, ws + O_SC, ws + O_S1P);
    conv2_kernel<<<2048, 256, 0, stream>>>(ws + O_S1P, ws + O_W2T, ws + O_S2C);
    stats_partial<<<1024, 256, 0, stream>>>(ws + O_S2C, 2048 * 169 * 32, ws + O_PART);
    reduce_part64<<<64, 256, 0, stream>>>(ws + O_PART, 1024, ws + O_PART2);
    finalize_stats<<<1, 256, 0, stream>>>(ws + O_PART2, 64, 1.f / 346112.f,
                                          g2, be2, ws + O_SC + 64);
    bn_pool2<<<2048, 256, 0, stream>>>(ws + O_S2C, ws + O_SC + 64, ws + O_S2P);
    conv3_kernel<<<512, 256, 0, stream>>>(ws + O_S2P, ws + O_W3T, ws + O_S3C);
    stats_partial<<<256, 256, 0, stream>>>(ws + O_S3C, 2048 * 16 * 32, ws + O_PART);
    reduce_part64<<<64, 256, 0, stream>>>(ws + O_PART, 256, ws + O_PART2);
    finalize_stats<<<1, 256, 0, stream>>>(ws + O_PART2, 64, 1.f / 32768.f,
                                          g3, be3, ws + O_SC + 128);
    bn_pool3_h0<<<1024, 256, 0, stream>>>(ws + O_S3C, ws + O_SC + 128, ws + O_H0);

    // ---- beam search ----
    beam0_kernel<<<2048, 64, 0, stream>>>(ws + O_H0, Who, bho, ws + O_SCORES,
                                          (int*)(ws + O_OP0), ws + O_P0);
    h_update<<<4096, 256, 0, stream>>>(ws + O_H0, 0, (int*)(ws + O_SRC2),
                                       (int*)(ws + O_OP0), Whh, Eop, bh, ws + O_H);
    beam_level<<<2048, 64, 0, stream>>>(ws + O_H, Who, bho, ws + O_SCORES,
                                        (int*)(ws + O_OP1), ws + O_P1,
                                        (int*)(ws + O_SRC1));
    h_update<<<4096, 256, 0, stream>>>(ws + O_H, 1, (int*)(ws + O_SRC1),
                                       (int*)(ws + O_OP1), Whh, Eop, bh, ws + O_H2);
    beam_level<<<2048, 64, 0, stream>>>(ws + O_H2, Who, bho, ws + O_SCORES,
                                        (int*)(ws + O_OP2), ws + O_P2,
                                        (int*)(ws + O_SRC2));

    // ---- expert dispatch (3 rounds) + head ----
    dispatch_kernel<<<4096, 256, 0, stream>>>(ws + O_H0, 0, (int*)(ws + O_OP0),
                                              ws + O_P0, expw, expb, ws + O_HIDA);
    dispatch_kernel<<<4096, 256, 0, stream>>>(ws + O_HIDA, 1, (int*)(ws + O_OP1),
                                              ws + O_P1, expw, expb, ws + O_HIDB);
    dispatch_kernel<<<4096, 256, 0, stream>>>(ws + O_HIDB, 1, (int*)(ws + O_OP2),
                                              ws + O_P2, expw, expb, ws + O_HIDA);
    final_kernel<<<320, 256, 0, stream>>>(ws + O_HIDA, outw, outb, out);
}

// Round 8
// 497.141 us; speedup vs baseline: 1.4114x; 1.0037x over previous
//
#include <hip/hip_runtime.h>
#include <cstdint>

// ============================================================================
// Supernetwork: conv-bn-relu-pool x3 backbone -> beam search -> expert dispatch
// All compute in fp32 (bf16 MFMA would flip beam-search top_k orderings).
// Intermediates NHWC. Conv bias omitted (cancelled exactly by BN mean-sub).
// R9: conv2/conv3 LDS swizzle strengthened: slot = cb ^ (Q&7) ^ ((Q>>3)&7).
// R8's cb^(Q&7) used only 3 bits of the pixel index -> lanes with pixels
// 8 apart aliased to one bank-quad: 1.3e7 conflict-cycles/dispatch = +7.3
// cyc per b128 read; LDS-pipe demand ~90 us matched conv2's measured 89 us.
// The extra (Q>>3) XOR spreads those lanes; residual aliasing <=2-way (free).
// Address permutation only -> bitwise-identical output.
// ============================================================================

// ---- ws layout (in floats) ----
static constexpr size_t O_SC    = 0;        // 192: [sc1|sh1|sc2|sh2|sc3|sh3] (64 each stage)
static constexpr size_t O_W1T   = 256;      // 864   w1t[k*32+co], k=ci*9+kh*3+kw
static constexpr size_t O_W2T   = 1152;     // 9216  w2t[k*32+co], k=(kh*3+kw)*32+ci
static constexpr size_t O_W3T   = 10368;    // 9216
static constexpr size_t O_SCORES= 19584;    // 8192
static constexpr size_t O_P0    = 27776;    // 8192 each
static constexpr size_t O_P1    = 35968;
static constexpr size_t O_P2    = 44160;
static constexpr size_t O_OP0   = 52352;    // int32, 8192 each
static constexpr size_t O_OP1   = 60544;
static constexpr size_t O_OP2   = 68736;
static constexpr size_t O_SRC1  = 76928;    // int32
static constexpr size_t O_SRC2  = 85120;
static constexpr size_t O_H0    = 93312;    // 2048*128
static constexpr size_t O_H     = 355456;   // 8192*128 (beam h; reused as stats partials in backbone)
static constexpr size_t O_H2    = 1404032;  // 8192*128
static constexpr size_t O_HIDA  = 2452608;  // 8192*128
static constexpr size_t O_HIDB  = 3501184;  // 8192*128
static constexpr size_t O_S1P   = 4549760;  // 2048*225*32 NHWC
static constexpr size_t O_S2C   = 19295360; // 2048*169*32 NHWC
static constexpr size_t O_S2P   = 30371968; // 2048*36*32  NHWC
static constexpr size_t O_S3C   = 32731264; // 2048*16*32  NHWC
static constexpr size_t O_PART  = O_H;      // per-block stats partials (max 2048*64)
static constexpr size_t O_PART2 = O_H + 131072;  // 64*64 second-level partials
// total 33779840 floats = 135.1 MB

__device__ __forceinline__ int swz8(int Q, int cb) {
    return cb ^ (Q & 7) ^ ((Q >> 3) & 7);
}

// ---------------------------------------------------------------------------
// K0: transpose conv weights to k-major [k][co] once per call
// ---------------------------------------------------------------------------
__global__ void prep_w(const float* __restrict__ w1, const float* __restrict__ w2,
                       const float* __restrict__ w3, float* __restrict__ w1t,
                       float* __restrict__ w2t, float* __restrict__ w3t) {
    int t = blockIdx.x * 256 + threadIdx.x;
    if (t < 864) {                       // w1 OIHW (32,3,3,3): k = ci*9+tap
        int co = t / 27, k = t % 27;
        w1t[k * 32 + co] = w1[t];
    }
    if (t < 9216) {                      // w2/w3 OIHW (32,32,3,3): k = tap*32+ci
        int co = t / 288, rest = t % 288;
        int ci = rest / 9, tap = rest % 9;
        int k = tap * 32 + ci;
        w2t[k * 32 + co] = w2[t];
        w3t[k * 32 + co] = w3[t];
    }
}

// ---------------------------------------------------------------------------
// reduce_part64: level-1 reduction of part[nblocks][64] -> part2[64][64].
// Block b sums rows i === b (mod 64). 64 blocks x 256 thr (4 row-groups).
// ---------------------------------------------------------------------------
__global__ __launch_bounds__(256) void reduce_part64(
    const float* __restrict__ part, int nblocks, float* __restrict__ part2) {
    __shared__ float red[256];
    const int b = blockIdx.x, t = threadIdx.x;
    const int c = t & 63, grp = t >> 6;
    float s = 0.f;
    for (int i = b + 64 * grp; i < nblocks; i += 256)
        s += part[(size_t)i * 64 + c];
    red[t] = s;
    __syncthreads();
    if (t < 64)
        part2[(size_t)b * 64 + t] =
            red[t] + red[64 + t] + red[128 + t] + red[192 + t];
}

// ---------------------------------------------------------------------------
// finalize_stats: reduce per-block partials [nblocks][64] (sum32|sq32) and
// write sc/sh (64 floats). 1 block, 256 threads. (Now always nblocks=64.)
// ---------------------------------------------------------------------------
__global__ __launch_bounds__(256) void finalize_stats(
    const float* __restrict__ part, int nblocks, float invcount,
    const float* __restrict__ g, const float* __restrict__ be,
    float* __restrict__ scsh) {
    __shared__ float red[256];
    const int t = threadIdx.x;
    const int c = t & 63, grp = t >> 6;
    float s = 0.f;
    for (int i = grp; i < nblocks; i += 4) s += part[(size_t)i * 64 + c];
    red[t] = s;
    __syncthreads();
    if (t < 64) red[t] = red[t] + red[64 + t] + red[128 + t] + red[192 + t];
    __syncthreads();
    if (t < 32) {
        float mean = red[t] * invcount;
        float var = red[32 + t] * invcount - mean * mean;
        float sc = g[t] * rsqrtf(var + 1e-5f);
        scsh[t] = sc;
        scsh[32 + t] = be[t] - mean * sc;
    }
}

// ---------------------------------------------------------------------------
// conv1 shared pieces. img4 LDS layout: [32 rows][32 slots], slot = even cols
// 0..15 (c=0,2,..30), odd cols 16..31 (c=1,3,..31). One float4 = (c0,c1,c2,0).
// CONV1_STAGE: cooperative fill from x NCHW (3,32,32).
// CONV1_PQUAD: conv outputs y[4][8] for the 2x2 conv-px quad of pooled pixel
// (ph,pw). Tap-row major: hoist 8 window float4s, stream (tc,ci): one 8-wide
// weight pair -> 32 fmacs -> dead. Per-pixel accum order tap-major, ci-inner.
// ---------------------------------------------------------------------------
#define CONV1_STAGE(img4, xin, t)                                              \
    for (int i = (t); i < 1024; i += 256) {                                    \
        int slot = (i & 1) * 16 + ((i & 31) >> 1);                             \
        img4[(i >> 5) * 32 + slot] =                                           \
            make_float4(xin[i], xin[1024 + i], xin[2048 + i], 0.f);            \
    }

__device__ __forceinline__ float f4c(float4 v, int ci) {
    return ci == 0 ? v.x : (ci == 1 ? v.y : v.z);
}

#define CONV1_PQUAD(img4, wb, ph, pw, y)                                       \
    {                                                                          \
        _Pragma("unroll")                                                      \
        for (int tr = 0; tr < 3; ++tr) {                                       \
            const int rb_ = (2 * (ph) + tr) * 32 + (pw);                       \
            float4 a0_[4], a1_[4];                                             \
            a0_[0] = img4[rb_ + 0];  a0_[1] = img4[rb_ + 16];                  \
            a0_[2] = img4[rb_ + 1];  a0_[3] = img4[rb_ + 17];                  \
            a1_[0] = img4[rb_ + 32]; a1_[1] = img4[rb_ + 48];                  \
            a1_[2] = img4[rb_ + 33]; a1_[3] = img4[rb_ + 49];                  \
            _Pragma("unroll")                                                  \
            for (int tc = 0; tc < 3; ++tc) {                                   \
                _Pragma("unroll")                                              \
                for (int ci = 0; ci < 3; ++ci) {                               \
                    const float* w8_ = (wb) + (ci * 9 + tr * 3 + tc) * 32;     \
                    float4 wa_ = *(const float4*)w8_;                          \
                    float4 wq_ = *(const float4*)(w8_ + 4);                    \
                    float wr_[8] = {wa_.x, wa_.y, wa_.z, wa_.w,                \
                                    wq_.x, wq_.y, wq_.z, wq_.w};               \
                    const float s00_ = f4c(a0_[tc], ci);                       \
                    const float s01_ = f4c(a0_[tc + 1], ci);                   \
                    const float s10_ = f4c(a1_[tc], ci);                       \
                    const float s11_ = f4c(a1_[tc + 1], ci);                   \
                    _Pragma("unroll")                                          \
                    for (int cc = 0; cc < 8; ++cc) {                           \
                        y[0][cc] += s00_ * wr_[cc];                            \
                        y[1][cc] += s01_ * wr_[cc];                            \
                        y[2][cc] += s10_ * wr_[cc];                            \
                        y[3][cc] += s11_ * wr_[cc];                            \
                    }                                                          \
                }                                                              \
            }                                                                  \
        }                                                                      \
    }

// ---------------------------------------------------------------------------
// K1: conv1 stats pass. 1 img/block, 256 thr = 4 waves (ch groups of 8).
// ---------------------------------------------------------------------------
__global__ __launch_bounds__(256, 4) void conv1_stats_kernel(
    const float* __restrict__ x, const float* __restrict__ w1t,
    float* __restrict__ part) {
    __shared__ float4 img4[1024];   // 16 KB
    const int n = blockIdx.x, t = threadIdx.x;
    const float* xin = x + (size_t)n * 3072;
    CONV1_STAGE(img4, xin, t)
    const int wv = t >> 6, lane = t & 63;
    const int c0s = __builtin_amdgcn_readfirstlane(wv * 8);
    const float* __restrict__ wb = w1t + c0s;
    __syncthreads();
    float sm[8] = {}, sq[8] = {};
#pragma unroll 1
    for (int j = 0; j < 4; ++j) {
        const int pp = lane + 64 * j;
        const bool pv = pp < 225;
        const int pc = pv ? pp : 0;
        const int ph = pc / 15, pw = pc % 15;
        float y[4][8] = {};
        CONV1_PQUAD(img4, wb, ph, pw, y)
        if (pv) {
#pragma unroll
            for (int q = 0; q < 4; ++q)
#pragma unroll
                for (int cc = 0; cc < 8; ++cc) {
                    float v = y[q][cc];
                    sm[cc] += v; sq[cc] += v * v;
                }
        }
    }
#pragma unroll
    for (int off = 32; off > 0; off >>= 1)
#pragma unroll
        for (int cc = 0; cc < 8; ++cc) {
            sm[cc] += __shfl_down(sm[cc], off);
            sq[cc] += __shfl_down(sq[cc], off);
        }
    if (lane == 0) {
        float* dst = part + (size_t)n * 64;
#pragma unroll
        for (int cc = 0; cc < 8; ++cc) {
            dst[c0s + cc] = sm[cc];
            dst[32 + c0s + cc] = sq[cc];
        }
    }
}

// ---------------------------------------------------------------------------
// K2: conv1 recompute + BN + relu + avgpool2 -> s1_pool NHWC (2048,15,15,32)
// ---------------------------------------------------------------------------
__global__ __launch_bounds__(256, 4) void conv1_apply_kernel(
    const float* __restrict__ x, const float* __restrict__ w1t,
    const float* __restrict__ scsh, float* __restrict__ s1p) {
    __shared__ float4 img4[1024];
    const int n = blockIdx.x, t = threadIdx.x;
    const float* xin = x + (size_t)n * 3072;
    CONV1_STAGE(img4, xin, t)
    const int wv = t >> 6, lane = t & 63;
    const int c0s = __builtin_amdgcn_readfirstlane(wv * 8);
    const float* __restrict__ wb = w1t + c0s;
    float scv[8], shv[8];
#pragma unroll
    for (int cc = 0; cc < 8; ++cc) {
        scv[cc] = scsh[c0s + cc];
        shv[cc] = scsh[32 + c0s + cc];
    }
    __syncthreads();
#pragma unroll 1
    for (int j = 0; j < 4; ++j) {
        const int pp = lane + 64 * j;
        const bool pv = pp < 225;
        const int pc = pv ? pp : 0;
        const int ph = pc / 15, pw = pc % 15;
        float y[4][8] = {};
        CONV1_PQUAD(img4, wb, ph, pw, y)
        if (pv) {
            float ov[8];
#pragma unroll
            for (int cc = 0; cc < 8; ++cc) {
                float sc = scv[cc], sh = shv[cc];
                float a0 = fmaxf(y[0][cc] * sc + sh, 0.f);
                float a1 = fmaxf(y[1][cc] * sc + sh, 0.f);
                float a2 = fmaxf(y[2][cc] * sc + sh, 0.f);
                float a3 = fmaxf(y[3][cc] * sc + sh, 0.f);
                ov[cc] = 0.25f * (a0 + a1 + a2 + a3);
            }
            float* dst = s1p + ((size_t)n * 225 + pc) * 32 + c0s;
            *(float4*)dst = make_float4(ov[0], ov[1], ov[2], ov[3]);
            *(float4*)(dst + 4) = make_float4(ov[4], ov[5], ov[6], ov[7]);
        }
    }
}

// ---------------------------------------------------------------------------
// K3: conv2 NHWC (15,15,32)->(13,13,32). 1 img/block, 256 thr = 4 waves
// (ch groups). Lane owns pixels p = lane+64j (p<169). img in LDS as
// [225 px][8 float4-cb] with swz8 swizzle -> conflict-free b128 over ci.
// Weights scalar via readfirstlane'd c0 (no LDS buffer).
// ---------------------------------------------------------------------------
__global__ __launch_bounds__(256) void conv2_kernel(
    const float* __restrict__ s1p, const float* __restrict__ w2t,
    float* __restrict__ s2c) {
    __shared__ float4 img4[1800];  // 225*8 float4 = 28.8 KB
    const int n = blockIdx.x, t = threadIdx.x;
    const float4* src4 = (const float4*)(s1p + (size_t)n * 7200);
    for (int i = t; i < 1800; i += 256) {
        int p = i >> 3, cb = i & 7;
        img4[(p << 3) + swz8(p, cb)] = src4[i];
    }
    const int wv = t >> 6, lane = t & 63;
    const int c0s = __builtin_amdgcn_readfirstlane(wv * 8);
    const float* __restrict__ wbase = w2t + c0s;
    int pxv[3], in0[3];
    bool val[3];
#pragma unroll
    for (int j = 0; j < 3; ++j) {
        int p = lane + 64 * j;
        val[j] = p < 169;
        int pc = val[j] ? p : 0;
        pxv[j] = pc;
        in0[j] = (pc / 13) * 15 + (pc % 13);
    }
    float y[3][8] = {};
    __syncthreads();
#pragma unroll 1
    for (int tap = 0; tap < 9; ++tap) {
        const int dp = (tap / 3) * 15 + (tap % 3);
        int qb[3], qs[3];
#pragma unroll
        for (int j = 0; j < 3; ++j) {
            int q = in0[j] + dp;
            qb[j] = q << 3;
            qs[j] = (q & 7) ^ ((q >> 3) & 7);
        }
        const float* wk = wbase + tap * 1024;   // (tap*32 + ci)*32
#pragma unroll
        for (int cb = 0; cb < 8; ++cb) {
            float4 v0 = img4[qb[0] + (cb ^ qs[0])];
            float4 v1 = img4[qb[1] + (cb ^ qs[1])];
            float4 v2 = img4[qb[2] + (cb ^ qs[2])];
#pragma unroll
            for (int u = 0; u < 4; ++u) {
                const float* w8 = wk + (cb * 4 + u) * 32;
                float4 wa = *(const float4*)w8;
                float4 wb = *(const float4*)(w8 + 4);
                float wreg[8] = {wa.x, wa.y, wa.z, wa.w, wb.x, wb.y, wb.z, wb.w};
                float sv[3] = {((const float*)&v0)[u], ((const float*)&v1)[u],
                               ((const float*)&v2)[u]};
#pragma unroll
                for (int j = 0; j < 3; ++j)
#pragma unroll
                    for (int cc = 0; cc < 8; ++cc)
                        y[j][cc] += sv[j] * wreg[cc];
            }
        }
    }
#pragma unroll
    for (int j = 0; j < 3; ++j)
        if (val[j]) {
            float* dst = s2c + ((size_t)n * 169 + pxv[j]) * 32 + c0s;
            *(float4*)dst = make_float4(y[j][0], y[j][1], y[j][2], y[j][3]);
            *(float4*)(dst + 4) = make_float4(y[j][4], y[j][5], y[j][6], y[j][7]);
        }
}

// ---------------------------------------------------------------------------
// K6: conv3 NHWC (6,6,32)->(4,4,32). 4 img/block, 256 thr = 4 waves (ch
// groups); lane = (img 2b | px 4b). swz8 over P = im*36 + pixel.
// ---------------------------------------------------------------------------
__global__ __launch_bounds__(256) void conv3_kernel(
    const float* __restrict__ s2p, const float* __restrict__ w3t,
    float* __restrict__ s3c) {
    __shared__ float4 img4[1152];  // 4 img * 36 px * 8 = 18 KB
    const int n0 = blockIdx.x * 4, t = threadIdx.x;
    const float4* src4 = (const float4*)(s2p + (size_t)n0 * 1152);
    for (int i = t; i < 1152; i += 256) {
        int im = i / 288, rem = i - im * 288;
        int p = rem >> 3, cb = rem & 7;
        img4[im * 288 + (p << 3) + swz8(im * 36 + p, cb)] = src4[i];
    }
    const int wv = t >> 6, lane = t & 63;
    const int c0s = __builtin_amdgcn_readfirstlane(wv * 8);
    const float* __restrict__ wbase = w3t + c0s;
    const int im = lane >> 4, p = lane & 15;
    const int in0 = (p >> 2) * 6 + (p & 3);
    float y[8] = {};
    __syncthreads();
#pragma unroll 1
    for (int tap = 0; tap < 9; ++tap) {
        const int q = in0 + (tap / 3) * 6 + (tap % 3);
        const int P = im * 36 + q;
        const int qb = im * 288 + (q << 3);
        const int qs = (P & 7) ^ ((P >> 3) & 7);
        const float* wk = wbase + tap * 1024;
#pragma unroll
        for (int cb = 0; cb < 8; ++cb) {
            float4 v = img4[qb + (cb ^ qs)];
#pragma unroll
            for (int u = 0; u < 4; ++u) {
                const float* w8 = wk + (cb * 4 + u) * 32;
                float4 wa = *(const float4*)w8;
                float4 wb = *(const float4*)(w8 + 4);
                float wreg[8] = {wa.x, wa.y, wa.z, wa.w, wb.x, wb.y, wb.z, wb.w};
                float s = ((const float*)&v)[u];
#pragma unroll
                for (int cc = 0; cc < 8; ++cc) y[cc] += s * wreg[cc];
            }
        }
    }
    float* dst = s3c + ((size_t)(n0 + im) * 16 + p) * 32 + c0s;
    *(float4*)dst = make_float4(y[0], y[1], y[2], y[3]);
    *(float4*)(dst + 4) = make_float4(y[4], y[5], y[6], y[7]);
}

// ---------------------------------------------------------------------------
// K4/K7: per-channel sum & sumsq over NHWC buffer (C=32) -> per-block partials
// ---------------------------------------------------------------------------
__global__ void stats_partial(const float* __restrict__ buf, int total,
                              float* __restrict__ part) {
    __shared__ float rs[256], rq[256];
    const int t = threadIdx.x;
    float s = 0.f, q = 0.f;
    for (int i = blockIdx.x * 256 + t; i < total; i += gridDim.x * 256) {
        float v = buf[i];
        s += v; q += v * v;
    }
    rs[t] = s; rq[t] = q;
    __syncthreads();
    for (int off = 128; off >= 32; off >>= 1) {
        if (t < off) { rs[t] += rs[t + off]; rq[t] += rq[t + off]; }
        __syncthreads();
    }
    if (t < 32) {
        part[(size_t)blockIdx.x * 64 + t] = rs[t];
        part[(size_t)blockIdx.x * 64 + 32 + t] = rq[t];
    }
}

// ---------------------------------------------------------------------------
// K5: BN+relu+avgpool2 for stage2: s2_conv (13,13) -> s2_pool (6,6) NHWC
// ---------------------------------------------------------------------------
__global__ void bn_pool2(const float* __restrict__ s2c, const float* __restrict__ scsh,
                         float* __restrict__ s2p) {
    __shared__ float bn[64];
    const int t = threadIdx.x;
    if (t < 64) bn[t] = scsh[t];
    __syncthreads();
    for (int idx = blockIdx.x * blockDim.x + t; idx < 2359296;
         idx += gridDim.x * blockDim.x) {
        const int ci = idx & 31, rest = idx >> 5;
        const int pp = rest % 36, n = rest / 36;
        const int ph = pp / 6, pw = pp % 6;
        const float* b = s2c + ((size_t)n * 169 + (2 * ph) * 13 + 2 * pw) * 32 + ci;
        const float s = bn[ci], h = bn[32 + ci];
        float a0 = fmaxf(b[0] * s + h, 0.f);
        float a1 = fmaxf(b[32] * s + h, 0.f);
        float a2 = fmaxf(b[13 * 32] * s + h, 0.f);
        float a3 = fmaxf(b[14 * 32] * s + h, 0.f);
        s2p[idx] = 0.25f * (a0 + a1 + a2 + a3);
    }
}

// ---------------------------------------------------------------------------
// K8: BN+relu+avgpool2 for stage3 writing h0 in NCHW-flat order h0[n][c*4+h*2+w]
// ---------------------------------------------------------------------------
__global__ void bn_pool3_h0(const float* __restrict__ s3c, const float* __restrict__ scsh,
                            float* __restrict__ h0) {
    __shared__ float bn[64];
    const int t = threadIdx.x;
    if (t < 64) bn[t] = scsh[t];
    __syncthreads();
    const int idx = blockIdx.x * 256 + t;
    if (idx >= 262144) return;
    const int n = idx >> 7, rem = idx & 127;
    const int c = rem >> 2, q = rem & 3, ph = q >> 1, pw = q & 1;
    const float* b = s3c + ((size_t)n * 16 + 2 * ph * 4 + 2 * pw) * 32 + c;
    const float s = bn[c], h = bn[32 + c];
    float a0 = fmaxf(b[0] * s + h, 0.f);
    float a1 = fmaxf(b[32] * s + h, 0.f);
    float a2 = fmaxf(b[128] * s + h, 0.f);
    float a3 = fmaxf(b[160] * s + h, 0.f);
    h0[idx] = 0.25f * (a0 + a1 + a2 + a3);
}

// ---------------------------------------------------------------------------
// K9: beam level 0: logits0 = h0.Who + bho; softmax/logsoftmax; stable sort-4
// one wave per sample
// ---------------------------------------------------------------------------
__global__ void beam0_kernel(const float* __restrict__ h0, const float* __restrict__ Who,
                             const float* __restrict__ bho, float* __restrict__ scores,
                             int* __restrict__ op0, float* __restrict__ p0) {
    const int n = blockIdx.x, lane = threadIdx.x;
    const float* hr = h0 + (size_t)n * 128;
    float pt[4] = {};
    for (int i = lane; i < 128; i += 64) {
        float hv = hr[i];
        pt[0] += hv * Who[i * 4 + 0];
        pt[1] += hv * Who[i * 4 + 1];
        pt[2] += hv * Who[i * 4 + 2];
        pt[3] += hv * Who[i * 4 + 3];
    }
#pragma unroll
    for (int off = 32; off > 0; off >>= 1)
#pragma unroll
        for (int o = 0; o < 4; ++o) pt[o] += __shfl_down(pt[o], off);
    if (lane == 0) {
        float lg[4], e[4], probs[4], logp[4];
#pragma unroll
        for (int o = 0; o < 4; ++o) lg[o] = pt[o] + bho[o];
        float m = fmaxf(fmaxf(lg[0], lg[1]), fmaxf(lg[2], lg[3]));
        float sum = 0.f;
#pragma unroll
        for (int o = 0; o < 4; ++o) { e[o] = expf(lg[o] - m); sum += e[o]; }
        float lse = logf(sum);
#pragma unroll
        for (int o = 0; o < 4; ++o) {
            probs[o] = e[o] / sum;
            logp[o] = lg[o] - m - lse;
        }
        bool used[4] = {false, false, false, false};
        for (int slot = 0; slot < 4; ++slot) {
            int best = 0; float bv = -INFINITY;
            for (int o = 0; o < 4; ++o)
                if (!used[o] && logp[o] > bv) { bv = logp[o]; best = o; }
            used[best] = true;
            scores[n * 4 + slot] = bv;
            op0[n * 4 + slot] = best;
            p0[n * 4 + slot] = probs[best];
        }
    }
}

// ---------------------------------------------------------------------------
// K11/K13: beam level >=1: 16 cand = scores[b]+logp[b][o]; stable top-4
// one wave per sample
// ---------------------------------------------------------------------------
__global__ void beam_level(const float* __restrict__ h, const float* __restrict__ Who,
                           const float* __restrict__ bho, float* __restrict__ scores,
                           int* __restrict__ opL, float* __restrict__ pL,
                           int* __restrict__ srcL) {
    __shared__ float logits[16], cand[16], pr[16];
    const int n = blockIdx.x, l = threadIdx.x;
    const int b = l >> 4, o = (l >> 2) & 3, qt = l & 3;
    const float* hr = h + ((size_t)n * 4 + b) * 128;
    float s = 0.f;
    for (int k = qt * 32; k < qt * 32 + 32; ++k) s += hr[k] * Who[k * 4 + o];
    s += __shfl_xor(s, 1);
    s += __shfl_xor(s, 2);
    if (qt == 0) logits[b * 4 + o] = s + bho[o];
    __syncthreads();
    if (l < 4) {
        float lg[4];
#pragma unroll
        for (int o2 = 0; o2 < 4; ++o2) lg[o2] = logits[l * 4 + o2];
        float m = fmaxf(fmaxf(lg[0], lg[1]), fmaxf(lg[2], lg[3]));
        float e[4], sum = 0.f;
#pragma unroll
        for (int o2 = 0; o2 < 4; ++o2) { e[o2] = expf(lg[o2] - m); sum += e[o2]; }
        float lse = logf(sum);
        float sb = scores[n * 4 + l];
#pragma unroll
        for (int o2 = 0; o2 < 4; ++o2) {
            pr[l * 4 + o2] = e[o2] / sum;
            cand[l * 4 + o2] = sb + (lg[o2] - m - lse);
        }
    }
    __syncthreads();
    if (l == 0) {
        bool used[16];
#pragma unroll
        for (int f = 0; f < 16; ++f) used[f] = false;
        float ns[4], np[4]; int nop[4], nsrc[4];
        for (int slot = 0; slot < 4; ++slot) {
            int best = 0; float bv = -INFINITY;
            for (int f = 0; f < 16; ++f)
                if (!used[f] && cand[f] > bv) { bv = cand[f]; best = f; }
            used[best] = true;
            ns[slot] = bv; nsrc[slot] = best >> 2; nop[slot] = best & 3;
            np[slot] = pr[best];
        }
        for (int slot = 0; slot < 4; ++slot) {
            scores[n * 4 + slot] = ns[slot];
            opL[n * 4 + slot] = nop[slot];
            pL[n * 4 + slot] = np[slot];
            srcL[n * 4 + slot] = nsrc[slot];
        }
    }
}

// ---------------------------------------------------------------------------
// K10/K12: h = tanh(src_row @ W_hh + E_op[op] + b_h). 2 rows x 128 cols/block.
// mode 0: src row = h0[r>>2];  mode 1: src row = in[(r&~3)+srcL[r]]
// ---------------------------------------------------------------------------
__global__ __launch_bounds__(256) void h_update(
    const float* __restrict__ in, int mode, const int* __restrict__ srcL,
    const int* __restrict__ opL, const float* __restrict__ Whh,
    const float* __restrict__ Eop, const float* __restrict__ bh,
    float* __restrict__ out) {
    __shared__ float A[256];
    const int r0 = blockIdx.x * 2, t = threadIdx.x;
    const int row = t >> 7, j = t & 127;
    const int r = r0 + row;
    const float* src;
    if (mode == 0) src = in + (size_t)(r >> 2) * 128;
    else           src = in + (size_t)((r & ~3) + srcL[r]) * 128;
    A[t] = src[j];
    __syncthreads();
    float acc = 0.f;
#pragma unroll 8
    for (int k = 0; k < 128; ++k) acc += A[row * 128 + k] * Whh[k * 128 + j];
    out[(size_t)r * 128 + j] = tanhf(acc + Eop[opL[r] * 128 + j] + bh[j]);
}

// ---------------------------------------------------------------------------
// K14-16: dispatch: per row apply only the SELECTED expert (op<3) or identity.
// out = relu((hid @ exp_w[op] + exp_b[op]) * p)  |  relu(hid * p)
// ---------------------------------------------------------------------------
__global__ __launch_bounds__(256) void dispatch_kernel(
    const float* __restrict__ in, int mode, const int* __restrict__ opL,
    const float* __restrict__ pL, const float* __restrict__ expw,
    const float* __restrict__ expb, float* __restrict__ out) {
    __shared__ float A[256];
    const int r0 = blockIdx.x * 2, t = threadIdx.x;
    const int row = t >> 7, j = t & 127;
    const int r = r0 + row;
    const float* src = (mode == 0) ? in + (size_t)(r >> 2) * 128
                                   : in + (size_t)r * 128;
    A[t] = src[j];
    __syncthreads();
    const int op = opL[r];
    const float p = pL[r];
    float res;
    if (op < 3) {
        const float* Bw = expw + (size_t)op * 16384;
        float acc = 0.f;
#pragma unroll 8
        for (int k = 0; k < 128; ++k) acc += A[row * 128 + k] * Bw[k * 128 + j];
        res = (acc + expb[op * 128 + j]) * p;
    } else {
        res = A[row * 128 + j] * p;
    }
    out[(size_t)r * 128 + j] = fmaxf(res, 0.f);
}

// ---------------------------------------------------------------------------
// K17: final head: out = hid @ out_w + out_b  (8192 x 10)
// ---------------------------------------------------------------------------
__global__ void final_kernel(const float* __restrict__ hid, const float* __restrict__ ow,
                             const float* __restrict__ ob, float* __restrict__ out) {
    const int idx = blockIdx.x * 256 + threadIdx.x;
    if (idx >= 81920) return;
    const int r = idx / 10, o = idx % 10;
    const float* hr = hid + (size_t)r * 128;
    float acc = ob[o];
#pragma unroll 8
    for (int k = 0; k < 128; ++k) acc += hr[k] * ow[k * 10 + o];
    out[idx] = acc;
}

// ===========================================================================
extern "C" void kernel_launch(void* const* d_in, const int* in_sizes, int n_in,
                              void* d_out, int out_size, void* d_ws, size_t ws_size,
                              hipStream_t stream) {
    const float* x    = (const float*)d_in[0];
    const float* cw1  = (const float*)d_in[1];
    const float* g1   = (const float*)d_in[3];
    const float* be1  = (const float*)d_in[4];
    const float* cw2  = (const float*)d_in[5];
    const float* g2   = (const float*)d_in[7];
    const float* be2  = (const float*)d_in[8];
    const float* cw3  = (const float*)d_in[9];
    const float* g3   = (const float*)d_in[11];
    const float* be3  = (const float*)d_in[12];
    const float* Whh  = (const float*)d_in[13];
    const float* bh   = (const float*)d_in[14];
    const float* Eop  = (const float*)d_in[15];
    const float* Who  = (const float*)d_in[16];
    const float* bho  = (const float*)d_in[17];
    const float* expw = (const float*)d_in[18];
    const float* expb = (const float*)d_in[19];
    const float* outw = (const float*)d_in[20];
    const float* outb = (const float*)d_in[21];
    float* ws  = (float*)d_ws;
    float* out = (float*)d_out;

    prep_w<<<36, 256, 0, stream>>>(cw1, cw2, cw3, ws + O_W1T, ws + O_W2T, ws + O_W3T);

    // ---- backbone ----
    conv1_stats_kernel<<<2048, 256, 0, stream>>>(x, ws + O_W1T, ws + O_PART);
    reduce_part64<<<64, 256, 0, stream>>>(ws + O_PART, 2048, ws + O_PART2);
    finalize_stats<<<1, 256, 0, stream>>>(ws + O_PART2, 64, 1.f / 1843200.f,
                                          g1, be1, ws + O_SC);
    conv1_apply_kernel<<<2048, 256, 0, stream>>>(x, ws + O_W1T, ws + O_SC, ws + O_S1P);
    conv2_kernel<<<2048, 256, 0, stream>>>(ws + O_S1P, ws + O_W2T, ws + O_S2C);
    stats_partial<<<1024, 256, 0, stream>>>(ws + O_S2C, 2048 * 169 * 32, ws + O_PART);
    reduce_part64<<<64, 256, 0, stream>>>(ws + O_PART, 1024, ws + O_PART2);
    finalize_stats<<<1, 256, 0, stream>>>(ws + O_PART2, 64, 1.f / 346112.f,
                                          g2, be2, ws + O_SC + 64);
    bn_pool2<<<2048, 256, 0, stream>>>(ws + O_S2C, ws + O_SC + 64, ws + O_S2P);
    conv3_kernel<<<512, 256, 0, stream>>>(ws + O_S2P, ws + O_W3T, ws + O_S3C);
    stats_partial<<<256, 256, 0, stream>>>(ws + O_S3C, 2048 * 16 * 32, ws + O_PART);
    reduce_part64<<<64, 256, 0, stream>>>(ws + O_PART, 256, ws + O_PART2);
    finalize_stats<<<1, 256, 0, stream>>>(ws + O_PART2, 64, 1.f / 32768.f,
                                          g3, be3, ws + O_SC + 128);
    bn_pool3_h0<<<1024, 256, 0, stream>>>(ws + O_S3C, ws + O_SC + 128, ws + O_H0);

    // ---- beam search ----
    beam0_kernel<<<2048, 64, 0, stream>>>(ws + O_H0, Who, bho, ws + O_SCORES,
                                          (int*)(ws + O_OP0), ws + O_P0);
    h_update<<<4096, 256, 0, stream>>>(ws + O_H0, 0, (int*)(ws + O_SRC2),
                                       (int*)(ws + O_OP0), Whh, Eop, bh, ws + O_H);
    beam_level<<<2048, 64, 0, stream>>>(ws + O_H, Who, bho, ws + O_SCORES,
                                        (int*)(ws + O_OP1), ws + O_P1,
                                        (int*)(ws + O_SRC1));
    h_update<<<4096, 256, 0, stream>>>(ws + O_H, 1, (int*)(ws + O_SRC1),
                                       (int*)(ws + O_OP1), Whh, Eop, bh, ws + O_H2);
    beam_level<<<2048, 64, 0, stream>>>(ws + O_H2, Who, bho, ws + O_SCORES,
                                        (int*)(ws + O_OP2), ws + O_P2,
                                        (int*)(ws + O_SRC2));

    // ---- expert dispatch (3 rounds) + head ----
    dispatch_kernel<<<4096, 256, 0, stream>>>(ws + O_H0, 0, (int*)(ws + O_OP0),
                                              ws + O_P0, expw, expb, ws + O_HIDA);
    dispatch_kernel<<<4096, 256, 0, stream>>>(ws + O_HIDA, 1, (int*)(ws + O_OP1),
                                              ws + O_P1, expw, expb, ws + O_HIDB);
    dispatch_kernel<<<4096, 256, 0, stream>>>(ws + O_HIDB, 1, (int*)(ws + O_OP2),
                                              ws + O_P2, expw, expb, ws + O_HIDA);
    final_kernel<<<320, 256, 0, stream>>>(ws + O_HIDA, outw, outb, out);
}

// Round 9
// 479.321 us; speedup vs baseline: 1.4639x; 1.0372x over previous
//
#include <hip/hip_runtime.h>
#include <cstdint>

// ============================================================================
// Supernetwork: conv-bn-relu-pool x3 backbone -> beam search -> expert dispatch
// All compute in fp32 (bf16 MFMA would flip beam-search top_k orderings).
// Intermediates NHWC. Conv bias omitted (cancelled exactly by BN mean-sub).
// R10: (a) BN-stats fused into conv2/conv3 (outputs are already in registers;
// per-wave shfl reduce + per-block partials) -- removes both stats_partial
// kernels (44 MB + 4 MB HBM re-reads + 2 launch gaps). (b) conv2 gets
// launch_bounds(256,5): R9 showed VGPR=44 with 39% occupancy -- the frugal
// allocation bought nothing (LDS permits 5 blocks/CU) and starved ILP; a
// 102-reg budget lets the compiler pipeline the per-tap LDS reads.
// R9's conflict lesson: -25% conflicts moved time 0% -> conflicts not binding.
// ============================================================================

// ---- ws layout (in floats) ----
static constexpr size_t O_SC    = 0;        // 192: [sc1|sh1|sc2|sh2|sc3|sh3] (64 each stage)
static constexpr size_t O_W1T   = 256;      // 864   w1t[k*32+co], k=ci*9+kh*3+kw
static constexpr size_t O_W2T   = 1152;     // 9216  w2t[k*32+co], k=(kh*3+kw)*32+ci
static constexpr size_t O_W3T   = 10368;    // 9216
static constexpr size_t O_SCORES= 19584;    // 8192
static constexpr size_t O_P0    = 27776;    // 8192 each
static constexpr size_t O_P1    = 35968;
static constexpr size_t O_P2    = 44160;
static constexpr size_t O_OP0   = 52352;    // int32, 8192 each
static constexpr size_t O_OP1   = 60544;
static constexpr size_t O_OP2   = 68736;
static constexpr size_t O_SRC1  = 76928;    // int32
static constexpr size_t O_SRC2  = 85120;
static constexpr size_t O_H0    = 93312;    // 2048*128
static constexpr size_t O_H     = 355456;   // 8192*128 (beam h; reused as stats partials in backbone)
static constexpr size_t O_H2    = 1404032;  // 8192*128
static constexpr size_t O_HIDA  = 2452608;  // 8192*128
static constexpr size_t O_HIDB  = 3501184;  // 8192*128
static constexpr size_t O_S1P   = 4549760;  // 2048*225*32 NHWC
static constexpr size_t O_S2C   = 19295360; // 2048*169*32 NHWC
static constexpr size_t O_S2P   = 30371968; // 2048*36*32  NHWC
static constexpr size_t O_S3C   = 32731264; // 2048*16*32  NHWC
static constexpr size_t O_PART  = O_H;      // per-block stats partials (max 2048*64)
static constexpr size_t O_PART2 = O_H + 131072;  // 64*64 second-level partials
// total 33779840 floats = 135.1 MB

__device__ __forceinline__ int swz8(int Q, int cb) {
    return cb ^ (Q & 7) ^ ((Q >> 3) & 7);
}

// ---------------------------------------------------------------------------
// K0: transpose conv weights to k-major [k][co] once per call
// ---------------------------------------------------------------------------
__global__ void prep_w(const float* __restrict__ w1, const float* __restrict__ w2,
                       const float* __restrict__ w3, float* __restrict__ w1t,
                       float* __restrict__ w2t, float* __restrict__ w3t) {
    int t = blockIdx.x * 256 + threadIdx.x;
    if (t < 864) {                       // w1 OIHW (32,3,3,3): k = ci*9+tap
        int co = t / 27, k = t % 27;
        w1t[k * 32 + co] = w1[t];
    }
    if (t < 9216) {                      // w2/w3 OIHW (32,32,3,3): k = tap*32+ci
        int co = t / 288, rest = t % 288;
        int ci = rest / 9, tap = rest % 9;
        int k = tap * 32 + ci;
        w2t[k * 32 + co] = w2[t];
        w3t[k * 32 + co] = w3[t];
    }
}

// ---------------------------------------------------------------------------
// reduce_part64: level-1 reduction of part[nblocks][64] -> part2[64][64].
// Block b sums rows i === b (mod 64). 64 blocks x 256 thr (4 row-groups).
// ---------------------------------------------------------------------------
__global__ __launch_bounds__(256) void reduce_part64(
    const float* __restrict__ part, int nblocks, float* __restrict__ part2) {
    __shared__ float red[256];
    const int b = blockIdx.x, t = threadIdx.x;
    const int c = t & 63, grp = t >> 6;
    float s = 0.f;
    for (int i = b + 64 * grp; i < nblocks; i += 256)
        s += part[(size_t)i * 64 + c];
    red[t] = s;
    __syncthreads();
    if (t < 64)
        part2[(size_t)b * 64 + t] =
            red[t] + red[64 + t] + red[128 + t] + red[192 + t];
}

// ---------------------------------------------------------------------------
// finalize_stats: reduce per-block partials [nblocks][64] (sum32|sq32) and
// write sc/sh (64 floats). 1 block, 256 threads. (Always nblocks=64 now.)
// ---------------------------------------------------------------------------
__global__ __launch_bounds__(256) void finalize_stats(
    const float* __restrict__ part, int nblocks, float invcount,
    const float* __restrict__ g, const float* __restrict__ be,
    float* __restrict__ scsh) {
    __shared__ float red[256];
    const int t = threadIdx.x;
    const int c = t & 63, grp = t >> 6;
    float s = 0.f;
    for (int i = grp; i < nblocks; i += 4) s += part[(size_t)i * 64 + c];
    red[t] = s;
    __syncthreads();
    if (t < 64) red[t] = red[t] + red[64 + t] + red[128 + t] + red[192 + t];
    __syncthreads();
    if (t < 32) {
        float mean = red[t] * invcount;
        float var = red[32 + t] * invcount - mean * mean;
        float sc = g[t] * rsqrtf(var + 1e-5f);
        scsh[t] = sc;
        scsh[32 + t] = be[t] - mean * sc;
    }
}

// ---------------------------------------------------------------------------
// conv1 shared pieces. img4 LDS layout: [32 rows][32 slots], slot = even cols
// 0..15 (c=0,2,..30), odd cols 16..31 (c=1,3,..31). One float4 = (c0,c1,c2,0).
// CONV1_STAGE: cooperative fill from x NCHW (3,32,32).
// CONV1_PQUAD: conv outputs y[4][8] for the 2x2 conv-px quad of pooled pixel
// (ph,pw). Tap-row major: hoist 8 window float4s, stream (tc,ci): one 8-wide
// weight pair -> 32 fmacs -> dead. Per-pixel accum order tap-major, ci-inner.
// ---------------------------------------------------------------------------
#define CONV1_STAGE(img4, xin, t)                                              \
    for (int i = (t); i < 1024; i += 256) {                                    \
        int slot = (i & 1) * 16 + ((i & 31) >> 1);                             \
        img4[(i >> 5) * 32 + slot] =                                           \
            make_float4(xin[i], xin[1024 + i], xin[2048 + i], 0.f);            \
    }

__device__ __forceinline__ float f4c(float4 v, int ci) {
    return ci == 0 ? v.x : (ci == 1 ? v.y : v.z);
}

#define CONV1_PQUAD(img4, wb, ph, pw, y)                                       \
    {                                                                          \
        _Pragma("unroll")                                                      \
        for (int tr = 0; tr < 3; ++tr) {                                       \
            const int rb_ = (2 * (ph) + tr) * 32 + (pw);                       \
            float4 a0_[4], a1_[4];                                             \
            a0_[0] = img4[rb_ + 0];  a0_[1] = img4[rb_ + 16];                  \
            a0_[2] = img4[rb_ + 1];  a0_[3] = img4[rb_ + 17];                  \
            a1_[0] = img4[rb_ + 32]; a1_[1] = img4[rb_ + 48];                  \
            a1_[2] = img4[rb_ + 33]; a1_[3] = img4[rb_ + 49];                  \
            _Pragma("unroll")                                                  \
            for (int tc = 0; tc < 3; ++tc) {                                   \
                _Pragma("unroll")                                              \
                for (int ci = 0; ci < 3; ++ci) {                               \
                    const float* w8_ = (wb) + (ci * 9 + tr * 3 + tc) * 32;     \
                    float4 wa_ = *(const float4*)w8_;                          \
                    float4 wq_ = *(const float4*)(w8_ + 4);                    \
                    float wr_[8] = {wa_.x, wa_.y, wa_.z, wa_.w,                \
                                    wq_.x, wq_.y, wq_.z, wq_.w};               \
                    const float s00_ = f4c(a0_[tc], ci);                       \
                    const float s01_ = f4c(a0_[tc + 1], ci);                   \
                    const float s10_ = f4c(a1_[tc], ci);                       \
                    const float s11_ = f4c(a1_[tc + 1], ci);                   \
                    _Pragma("unroll")                                          \
                    for (int cc = 0; cc < 8; ++cc) {                           \
                        y[0][cc] += s00_ * wr_[cc];                            \
                        y[1][cc] += s01_ * wr_[cc];                            \
                        y[2][cc] += s10_ * wr_[cc];                            \
                        y[3][cc] += s11_ * wr_[cc];                            \
                    }                                                          \
                }                                                              \
            }                                                                  \
        }                                                                      \
    }

// ---------------------------------------------------------------------------
// K1: conv1 stats pass. 1 img/block, 256 thr = 4 waves (ch groups of 8).
// ---------------------------------------------------------------------------
__global__ __launch_bounds__(256, 4) void conv1_stats_kernel(
    const float* __restrict__ x, const float* __restrict__ w1t,
    float* __restrict__ part) {
    __shared__ float4 img4[1024];   // 16 KB
    const int n = blockIdx.x, t = threadIdx.x;
    const float* xin = x + (size_t)n * 3072;
    CONV1_STAGE(img4, xin, t)
    const int wv = t >> 6, lane = t & 63;
    const int c0s = __builtin_amdgcn_readfirstlane(wv * 8);
    const float* __restrict__ wb = w1t + c0s;
    __syncthreads();
    float sm[8] = {}, sq[8] = {};
#pragma unroll 1
    for (int j = 0; j < 4; ++j) {
        const int pp = lane + 64 * j;
        const bool pv = pp < 225;
        const int pc = pv ? pp : 0;
        const int ph = pc / 15, pw = pc % 15;
        float y[4][8] = {};
        CONV1_PQUAD(img4, wb, ph, pw, y)
        if (pv) {
#pragma unroll
            for (int q = 0; q < 4; ++q)
#pragma unroll
                for (int cc = 0; cc < 8; ++cc) {
                    float v = y[q][cc];
                    sm[cc] += v; sq[cc] += v * v;
                }
        }
    }
#pragma unroll
    for (int off = 32; off > 0; off >>= 1)
#pragma unroll
        for (int cc = 0; cc < 8; ++cc) {
            sm[cc] += __shfl_down(sm[cc], off);
            sq[cc] += __shfl_down(sq[cc], off);
        }
    if (lane == 0) {
        float* dst = part + (size_t)n * 64;
#pragma unroll
        for (int cc = 0; cc < 8; ++cc) {
            dst[c0s + cc] = sm[cc];
            dst[32 + c0s + cc] = sq[cc];
        }
    }
}

// ---------------------------------------------------------------------------
// K2: conv1 recompute + BN + relu + avgpool2 -> s1_pool NHWC (2048,15,15,32)
// ---------------------------------------------------------------------------
__global__ __launch_bounds__(256, 4) void conv1_apply_kernel(
    const float* __restrict__ x, const float* __restrict__ w1t,
    const float* __restrict__ scsh, float* __restrict__ s1p) {
    __shared__ float4 img4[1024];
    const int n = blockIdx.x, t = threadIdx.x;
    const float* xin = x + (size_t)n * 3072;
    CONV1_STAGE(img4, xin, t)
    const int wv = t >> 6, lane = t & 63;
    const int c0s = __builtin_amdgcn_readfirstlane(wv * 8);
    const float* __restrict__ wb = w1t + c0s;
    float scv[8], shv[8];
#pragma unroll
    for (int cc = 0; cc < 8; ++cc) {
        scv[cc] = scsh[c0s + cc];
        shv[cc] = scsh[32 + c0s + cc];
    }
    __syncthreads();
#pragma unroll 1
    for (int j = 0; j < 4; ++j) {
        const int pp = lane + 64 * j;
        const bool pv = pp < 225;
        const int pc = pv ? pp : 0;
        const int ph = pc / 15, pw = pc % 15;
        float y[4][8] = {};
        CONV1_PQUAD(img4, wb, ph, pw, y)
        if (pv) {
            float ov[8];
#pragma unroll
            for (int cc = 0; cc < 8; ++cc) {
                float sc = scv[cc], sh = shv[cc];
                float a0 = fmaxf(y[0][cc] * sc + sh, 0.f);
                float a1 = fmaxf(y[1][cc] * sc + sh, 0.f);
                float a2 = fmaxf(y[2][cc] * sc + sh, 0.f);
                float a3 = fmaxf(y[3][cc] * sc + sh, 0.f);
                ov[cc] = 0.25f * (a0 + a1 + a2 + a3);
            }
            float* dst = s1p + ((size_t)n * 225 + pc) * 32 + c0s;
            *(float4*)dst = make_float4(ov[0], ov[1], ov[2], ov[3]);
            *(float4*)(dst + 4) = make_float4(ov[4], ov[5], ov[6], ov[7]);
        }
    }
}

// ---------------------------------------------------------------------------
// K3: conv2 NHWC (15,15,32)->(13,13,32) + fused BN-stats partials.
// 1 img/block, 256 thr = 4 waves (ch groups). Lane owns pixels p = lane+64j
// (p<169). img in LDS [225 px][8 float4-cb] with swz8. Weights scalar.
// launch_bounds(256,5): 102-reg budget for ILP; LDS permits 5 blocks/CU.
// ---------------------------------------------------------------------------
__global__ __launch_bounds__(256, 5) void conv2_kernel(
    const float* __restrict__ s1p, const float* __restrict__ w2t,
    float* __restrict__ s2c, float* __restrict__ part) {
    __shared__ float4 img4[1800];  // 225*8 float4 = 28.8 KB
    const int n = blockIdx.x, t = threadIdx.x;
    const float4* src4 = (const float4*)(s1p + (size_t)n * 7200);
    for (int i = t; i < 1800; i += 256) {
        int p = i >> 3, cb = i & 7;
        img4[(p << 3) + swz8(p, cb)] = src4[i];
    }
    const int wv = t >> 6, lane = t & 63;
    const int c0s = __builtin_amdgcn_readfirstlane(wv * 8);
    const float* __restrict__ wbase = w2t + c0s;
    int pxv[3], in0[3];
    bool val[3];
#pragma unroll
    for (int j = 0; j < 3; ++j) {
        int p = lane + 64 * j;
        val[j] = p < 169;
        int pc = val[j] ? p : 0;
        pxv[j] = pc;
        in0[j] = (pc / 13) * 15 + (pc % 13);
    }
    float y[3][8] = {};
    __syncthreads();
#pragma unroll 1
    for (int tap = 0; tap < 9; ++tap) {
        const int dp = (tap / 3) * 15 + (tap % 3);
        int qb[3], qs[3];
#pragma unroll
        for (int j = 0; j < 3; ++j) {
            int q = in0[j] + dp;
            qb[j] = q << 3;
            qs[j] = (q & 7) ^ ((q >> 3) & 7);
        }
        const float* wk = wbase + tap * 1024;   // (tap*32 + ci)*32
#pragma unroll
        for (int cb = 0; cb < 8; ++cb) {
            float4 v0 = img4[qb[0] + (cb ^ qs[0])];
            float4 v1 = img4[qb[1] + (cb ^ qs[1])];
            float4 v2 = img4[qb[2] + (cb ^ qs[2])];
#pragma unroll
            for (int u = 0; u < 4; ++u) {
                const float* w8 = wk + (cb * 4 + u) * 32;
                float4 wa = *(const float4*)w8;
                float4 wb = *(const float4*)(w8 + 4);
                float wreg[8] = {wa.x, wa.y, wa.z, wa.w, wb.x, wb.y, wb.z, wb.w};
                float sv[3] = {((const float*)&v0)[u], ((const float*)&v1)[u],
                               ((const float*)&v2)[u]};
#pragma unroll
                for (int j = 0; j < 3; ++j)
#pragma unroll
                    for (int cc = 0; cc < 8; ++cc)
                        y[j][cc] += sv[j] * wreg[cc];
            }
        }
    }
#pragma unroll
    for (int j = 0; j < 3; ++j)
        if (val[j]) {
            float* dst = s2c + ((size_t)n * 169 + pxv[j]) * 32 + c0s;
            *(float4*)dst = make_float4(y[j][0], y[j][1], y[j][2], y[j][3]);
            *(float4*)(dst + 4) = make_float4(y[j][4], y[j][5], y[j][6], y[j][7]);
        }
    // fused BN-stats partials (per-wave channels c0s..c0s+7)
    float sm[8] = {}, sq[8] = {};
#pragma unroll
    for (int j = 0; j < 3; ++j)
        if (val[j]) {
#pragma unroll
            for (int cc = 0; cc < 8; ++cc) {
                float v = y[j][cc];
                sm[cc] += v; sq[cc] += v * v;
            }
        }
#pragma unroll
    for (int off = 32; off > 0; off >>= 1)
#pragma unroll
        for (int cc = 0; cc < 8; ++cc) {
            sm[cc] += __shfl_down(sm[cc], off);
            sq[cc] += __shfl_down(sq[cc], off);
        }
    if (lane == 0) {
        float* dst = part + (size_t)n * 64;
#pragma unroll
        for (int cc = 0; cc < 8; ++cc) {
            dst[c0s + cc] = sm[cc];
            dst[32 + c0s + cc] = sq[cc];
        }
    }
}

// ---------------------------------------------------------------------------
// K6: conv3 NHWC (6,6,32)->(4,4,32) + fused BN-stats partials.
// 4 img/block, 256 thr = 4 waves (ch groups); lane = (img 2b | px 4b).
// ---------------------------------------------------------------------------
__global__ __launch_bounds__(256) void conv3_kernel(
    const float* __restrict__ s2p, const float* __restrict__ w3t,
    float* __restrict__ s3c, float* __restrict__ part) {
    __shared__ float4 img4[1152];  // 4 img * 36 px * 8 = 18 KB
    const int n0 = blockIdx.x * 4, t = threadIdx.x;
    const float4* src4 = (const float4*)(s2p + (size_t)n0 * 1152);
    for (int i = t; i < 1152; i += 256) {
        int im = i / 288, rem = i - im * 288;
        int p = rem >> 3, cb = rem & 7;
        img4[im * 288 + (p << 3) + swz8(im * 36 + p, cb)] = src4[i];
    }
    const int wv = t >> 6, lane = t & 63;
    const int c0s = __builtin_amdgcn_readfirstlane(wv * 8);
    const float* __restrict__ wbase = w3t + c0s;
    const int im = lane >> 4, p = lane & 15;
    const int in0 = (p >> 2) * 6 + (p & 3);
    float y[8] = {};
    __syncthreads();
#pragma unroll 1
    for (int tap = 0; tap < 9; ++tap) {
        const int q = in0 + (tap / 3) * 6 + (tap % 3);
        const int P = im * 36 + q;
        const int qb = im * 288 + (q << 3);
        const int qs = (P & 7) ^ ((P >> 3) & 7);
        const float* wk = wbase + tap * 1024;
#pragma unroll
        for (int cb = 0; cb < 8; ++cb) {
            float4 v = img4[qb + (cb ^ qs)];
#pragma unroll
            for (int u = 0; u < 4; ++u) {
                const float* w8 = wk + (cb * 4 + u) * 32;
                float4 wa = *(const float4*)w8;
                float4 wb = *(const float4*)(w8 + 4);
                float wreg[8] = {wa.x, wa.y, wa.z, wa.w, wb.x, wb.y, wb.z, wb.w};
                float s = ((const float*)&v)[u];
#pragma unroll
                for (int cc = 0; cc < 8; ++cc) y[cc] += s * wreg[cc];
            }
        }
    }
    float* dst = s3c + ((size_t)(n0 + im) * 16 + p) * 32 + c0s;
    *(float4*)dst = make_float4(y[0], y[1], y[2], y[3]);
    *(float4*)(dst + 4) = make_float4(y[4], y[5], y[6], y[7]);
    // fused BN-stats partials
    float sm[8], sq[8];
#pragma unroll
    for (int cc = 0; cc < 8; ++cc) {
        sm[cc] = y[cc]; sq[cc] = y[cc] * y[cc];
    }
#pragma unroll
    for (int off = 32; off > 0; off >>= 1)
#pragma unroll
        for (int cc = 0; cc < 8; ++cc) {
            sm[cc] += __shfl_down(sm[cc], off);
            sq[cc] += __shfl_down(sq[cc], off);
        }
    if (lane == 0) {
        float* dstp = part + (size_t)blockIdx.x * 64;
#pragma unroll
        for (int cc = 0; cc < 8; ++cc) {
            dstp[c0s + cc] = sm[cc];
            dstp[32 + c0s + cc] = sq[cc];
        }
    }
}

// ---------------------------------------------------------------------------
// K5: BN+relu+avgpool2 for stage2: s2_conv (13,13) -> s2_pool (6,6) NHWC
// ---------------------------------------------------------------------------
__global__ void bn_pool2(const float* __restrict__ s2c, const float* __restrict__ scsh,
                         float* __restrict__ s2p) {
    __shared__ float bn[64];
    const int t = threadIdx.x;
    if (t < 64) bn[t] = scsh[t];
    __syncthreads();
    for (int idx = blockIdx.x * blockDim.x + t; idx < 2359296;
         idx += gridDim.x * blockDim.x) {
        const int ci = idx & 31, rest = idx >> 5;
        const int pp = rest % 36, n = rest / 36;
        const int ph = pp / 6, pw = pp % 6;
        const float* b = s2c + ((size_t)n * 169 + (2 * ph) * 13 + 2 * pw) * 32 + ci;
        const float s = bn[ci], h = bn[32 + ci];
        float a0 = fmaxf(b[0] * s + h, 0.f);
        float a1 = fmaxf(b[32] * s + h, 0.f);
        float a2 = fmaxf(b[13 * 32] * s + h, 0.f);
        float a3 = fmaxf(b[14 * 32] * s + h, 0.f);
        s2p[idx] = 0.25f * (a0 + a1 + a2 + a3);
    }
}

// ---------------------------------------------------------------------------
// K8: BN+relu+avgpool2 for stage3 writing h0 in NCHW-flat order h0[n][c*4+h*2+w]
// ---------------------------------------------------------------------------
__global__ void bn_pool3_h0(const float* __restrict__ s3c, const float* __restrict__ scsh,
                            float* __restrict__ h0) {
    __shared__ float bn[64];
    const int t = threadIdx.x;
    if (t < 64) bn[t] = scsh[t];
    __syncthreads();
    const int idx = blockIdx.x * 256 + t;
    if (idx >= 262144) return;
    const int n = idx >> 7, rem = idx & 127;
    const int c = rem >> 2, q = rem & 3, ph = q >> 1, pw = q & 1;
    const float* b = s3c + ((size_t)n * 16 + 2 * ph * 4 + 2 * pw) * 32 + c;
    const float s = bn[c], h = bn[32 + c];
    float a0 = fmaxf(b[0] * s + h, 0.f);
    float a1 = fmaxf(b[32] * s + h, 0.f);
    float a2 = fmaxf(b[128] * s + h, 0.f);
    float a3 = fmaxf(b[160] * s + h, 0.f);
    h0[idx] = 0.25f * (a0 + a1 + a2 + a3);
}

// ---------------------------------------------------------------------------
// K9: beam level 0: logits0 = h0.Who + bho; softmax/logsoftmax; stable sort-4
// one wave per sample
// ---------------------------------------------------------------------------
__global__ void beam0_kernel(const float* __restrict__ h0, const float* __restrict__ Who,
                             const float* __restrict__ bho, float* __restrict__ scores,
                             int* __restrict__ op0, float* __restrict__ p0) {
    const int n = blockIdx.x, lane = threadIdx.x;
    const float* hr = h0 + (size_t)n * 128;
    float pt[4] = {};
    for (int i = lane; i < 128; i += 64) {
        float hv = hr[i];
        pt[0] += hv * Who[i * 4 + 0];
        pt[1] += hv * Who[i * 4 + 1];
        pt[2] += hv * Who[i * 4 + 2];
        pt[3] += hv * Who[i * 4 + 3];
    }
#pragma unroll
    for (int off = 32; off > 0; off >>= 1)
#pragma unroll
        for (int o = 0; o < 4; ++o) pt[o] += __shfl_down(pt[o], off);
    if (lane == 0) {
        float lg[4], e[4], probs[4], logp[4];
#pragma unroll
        for (int o = 0; o < 4; ++o) lg[o] = pt[o] + bho[o];
        float m = fmaxf(fmaxf(lg[0], lg[1]), fmaxf(lg[2], lg[3]));
        float sum = 0.f;
#pragma unroll
        for (int o = 0; o < 4; ++o) { e[o] = expf(lg[o] - m); sum += e[o]; }
        float lse = logf(sum);
#pragma unroll
        for (int o = 0; o < 4; ++o) {
            probs[o] = e[o] / sum;
            logp[o] = lg[o] - m - lse;
        }
        bool used[4] = {false, false, false, false};
        for (int slot = 0; slot < 4; ++slot) {
            int best = 0; float bv = -INFINITY;
            for (int o = 0; o < 4; ++o)
                if (!used[o] && logp[o] > bv) { bv = logp[o]; best = o; }
            used[best] = true;
            scores[n * 4 + slot] = bv;
            op0[n * 4 + slot] = best;
            p0[n * 4 + slot] = probs[best];
        }
    }
}

// ---------------------------------------------------------------------------
// K11/K13: beam level >=1: 16 cand = scores[b]+logp[b][o]; stable top-4
// one wave per sample
// ---------------------------------------------------------------------------
__global__ void beam_level(const float* __restrict__ h, const float* __restrict__ Who,
                           const float* __restrict__ bho, float* __restrict__ scores,
                           int* __restrict__ opL, float* __restrict__ pL,
                           int* __restrict__ srcL) {
    __shared__ float logits[16], cand[16], pr[16];
    const int n = blockIdx.x, l = threadIdx.x;
    const int b = l >> 4, o = (l >> 2) & 3, qt = l & 3;
    const float* hr = h + ((size_t)n * 4 + b) * 128;
    float s = 0.f;
    for (int k = qt * 32; k < qt * 32 + 32; ++k) s += hr[k] * Who[k * 4 + o];
    s += __shfl_xor(s, 1);
    s += __shfl_xor(s, 2);
    if (qt == 0) logits[b * 4 + o] = s + bho[o];
    __syncthreads();
    if (l < 4) {
        float lg[4];
#pragma unroll
        for (int o2 = 0; o2 < 4; ++o2) lg[o2] = logits[l * 4 + o2];
        float m = fmaxf(fmaxf(lg[0], lg[1]), fmaxf(lg[2], lg[3]));
        float e[4], sum = 0.f;
#pragma unroll
        for (int o2 = 0; o2 < 4; ++o2) { e[o2] = expf(lg[o2] - m); sum += e[o2]; }
        float lse = logf(sum);
        float sb = scores[n * 4 + l];
#pragma unroll
        for (int o2 = 0; o2 < 4; ++o2) {
            pr[l * 4 + o2] = e[o2] / sum;
            cand[l * 4 + o2] = sb + (lg[o2] - m - lse);
        }
    }
    __syncthreads();
    if (l == 0) {
        bool used[16];
#pragma unroll
        for (int f = 0; f < 16; ++f) used[f] = false;
        float ns[4], np[4]; int nop[4], nsrc[4];
        for (int slot = 0; slot < 4; ++slot) {
            int best = 0; float bv = -INFINITY;
            for (int f = 0; f < 16; ++f)
                if (!used[f] && cand[f] > bv) { bv = cand[f]; best = f; }
            used[best] = true;
            ns[slot] = bv; nsrc[slot] = best >> 2; nop[slot] = best & 3;
            np[slot] = pr[best];
        }
        for (int slot = 0; slot < 4; ++slot) {
            scores[n * 4 + slot] = ns[slot];
            opL[n * 4 + slot] = nop[slot];
            pL[n * 4 + slot] = np[slot];
            srcL[n * 4 + slot] = nsrc[slot];
        }
    }
}

// ---------------------------------------------------------------------------
// K10/K12: h = tanh(src_row @ W_hh + E_op[op] + b_h). 2 rows x 128 cols/block.
// mode 0: src row = h0[r>>2];  mode 1: src row = in[(r&~3)+srcL[r]]
// ---------------------------------------------------------------------------
__global__ __launch_bounds__(256) void h_update(
    const float* __restrict__ in, int mode, const int* __restrict__ srcL,
    const int* __restrict__ opL, const float* __restrict__ Whh,
    const float* __restrict__ Eop, const float* __restrict__ bh,
    float* __restrict__ out) {
    __shared__ float A[256];
    const int r0 = blockIdx.x * 2, t = threadIdx.x;
    const int row = t >> 7, j = t & 127;
    const int r = r0 + row;
    const float* src;
    if (mode == 0) src = in + (size_t)(r >> 2) * 128;
    else           src = in + (size_t)((r & ~3) + srcL[r]) * 128;
    A[t] = src[j];
    __syncthreads();
    float acc = 0.f;
#pragma unroll 8
    for (int k = 0; k < 128; ++k) acc += A[row * 128 + k] * Whh[k * 128 + j];
    out[(size_t)r * 128 + j] = tanhf(acc + Eop[opL[r] * 128 + j] + bh[j]);
}

// ---------------------------------------------------------------------------
// K14-16: dispatch: per row apply only the SELECTED expert (op<3) or identity.
// out = relu((hid @ exp_w[op] + exp_b[op]) * p)  |  relu(hid * p)
// ---------------------------------------------------------------------------
__global__ __launch_bounds__(256) void dispatch_kernel(
    const float* __restrict__ in, int mode, const int* __restrict__ opL,
    const float* __restrict__ pL, const float* __restrict__ expw,
    const float* __restrict__ expb, float* __restrict__ out) {
    __shared__ float A[256];
    const int r0 = blockIdx.x * 2, t = threadIdx.x;
    const int row = t >> 7, j = t & 127;
    const int r = r0 + row;
    const float* src = (mode == 0) ? in + (size_t)(r >> 2) * 128
                                   : in + (size_t)r * 128;
    A[t] = src[j];
    __syncthreads();
    const int op = opL[r];
    const float p = pL[r];
    float res;
    if (op < 3) {
        const float* Bw = expw + (size_t)op * 16384;
        float acc = 0.f;
#pragma unroll 8
        for (int k = 0; k < 128; ++k) acc += A[row * 128 + k] * Bw[k * 128 + j];
        res = (acc + expb[op * 128 + j]) * p;
    } else {
        res = A[row * 128 + j] * p;
    }
    out[(size_t)r * 128 + j] = fmaxf(res, 0.f);
}

// ---------------------------------------------------------------------------
// K17: final head: out = hid @ out_w + out_b  (8192 x 10)
// ---------------------------------------------------------------------------
__global__ void final_kernel(const float* __restrict__ hid, const float* __restrict__ ow,
                             const float* __restrict__ ob, float* __restrict__ out) {
    const int idx = blockIdx.x * 256 + threadIdx.x;
    if (idx >= 81920) return;
    const int r = idx / 10, o = idx % 10;
    const float* hr = hid + (size_t)r * 128;
    float acc = ob[o];
#pragma unroll 8
    for (int k = 0; k < 128; ++k) acc += hr[k] * ow[k * 10 + o];
    out[idx] = acc;
}

// ===========================================================================
extern "C" void kernel_launch(void* const* d_in, const int* in_sizes, int n_in,
                              void* d_out, int out_size, void* d_ws, size_t ws_size,
                              hipStream_t stream) {
    const float* x    = (const float*)d_in[0];
    const float* cw1  = (const float*)d_in[1];
    const float* g1   = (const float*)d_in[3];
    const float* be1  = (const float*)d_in[4];
    const float* cw2  = (const float*)d_in[5];
    const float* g2   = (const float*)d_in[7];
    const float* be2  = (const float*)d_in[8];
    const float* cw3  = (const float*)d_in[9];
    const float* g3   = (const float*)d_in[11];
    const float* be3  = (const float*)d_in[12];
    const float* Whh  = (const float*)d_in[13];
    const float* bh   = (const float*)d_in[14];
    const float* Eop  = (const float*)d_in[15];
    const float* Who  = (const float*)d_in[16];
    const float* bho  = (const float*)d_in[17];
    const float* expw = (const float*)d_in[18];
    const float* expb = (const float*)d_in[19];
    const float* outw = (const float*)d_in[20];
    const float* outb = (const float*)d_in[21];
    float* ws  = (float*)d_ws;
    float* out = (float*)d_out;

    prep_w<<<36, 256, 0, stream>>>(cw1, cw2, cw3, ws + O_W1T, ws + O_W2T, ws + O_W3T);

    // ---- backbone ----
    conv1_stats_kernel<<<2048, 256, 0, stream>>>(x, ws + O_W1T, ws + O_PART);
    reduce_part64<<<64, 256, 0, stream>>>(ws + O_PART, 2048, ws + O_PART2);
    finalize_stats<<<1, 256, 0, stream>>>(ws + O_PART2, 64, 1.f / 1843200.f,
                                          g1, be1, ws + O_SC);
    conv1_apply_kernel<<<2048, 256, 0, stream>>>(x, ws + O_W1T, ws + O_SC, ws + O_S1P);
    conv2_kernel<<<2048, 256, 0, stream>>>(ws + O_S1P, ws + O_W2T, ws + O_S2C,
                                           ws + O_PART);
    reduce_part64<<<64, 256, 0, stream>>>(ws + O_PART, 2048, ws + O_PART2);
    finalize_stats<<<1, 256, 0, stream>>>(ws + O_PART2, 64, 1.f / 346112.f,
                                          g2, be2, ws + O_SC + 64);
    bn_pool2<<<2048, 256, 0, stream>>>(ws + O_S2C, ws + O_SC + 64, ws + O_S2P);
    conv3_kernel<<<512, 256, 0, stream>>>(ws + O_S2P, ws + O_W3T, ws + O_S3C,
                                          ws + O_PART);
    reduce_part64<<<64, 256, 0, stream>>>(ws + O_PART, 512, ws + O_PART2);
    finalize_stats<<<1, 256, 0, stream>>>(ws + O_PART2, 64, 1.f / 32768.f,
                                          g3, be3, ws + O_SC + 128);
    bn_pool3_h0<<<1024, 256, 0, stream>>>(ws + O_S3C, ws + O_SC + 128, ws + O_H0);

    // ---- beam search ----
    beam0_kernel<<<2048, 64, 0, stream>>>(ws + O_H0, Who, bho, ws + O_SCORES,
                                          (int*)(ws + O_OP0), ws + O_P0);
    h_update<<<4096, 256, 0, stream>>>(ws + O_H0, 0, (int*)(ws + O_SRC2),
                                       (int*)(ws + O_OP0), Whh, Eop, bh, ws + O_H);
    beam_level<<<2048, 64, 0, stream>>>(ws + O_H, Who, bho, ws + O_SCORES,
                                        (int*)(ws + O_OP1), ws + O_P1,
                                        (int*)(ws + O_SRC1));
    h_update<<<4096, 256, 0, stream>>>(ws + O_H, 1, (int*)(ws + O_SRC1),
                                       (int*)(ws + O_OP1), Whh, Eop, bh, ws + O_H2);
    beam_level<<<2048, 64, 0, stream>>>(ws + O_H2, Who, bho, ws + O_SCORES,
                                        (int*)(ws + O_OP2), ws + O_P2,
                                        (int*)(ws + O_SRC2));

    // ---- expert dispatch (3 rounds) + head ----
    dispatch_kernel<<<4096, 256, 0, stream>>>(ws + O_H0, 0, (int*)(ws + O_OP0),
                                              ws + O_P0, expw, expb, ws + O_HIDA);
    dispatch_kernel<<<4096, 256, 0, stream>>>(ws + O_HIDA, 1, (int*)(ws + O_OP1),
                                              ws + O_P1, expw, expb, ws + O_HIDB);
    dispatch_kernel<<<4096, 256, 0, stream>>>(ws + O_HIDB, 1, (int*)(ws + O_OP2),
                                              ws + O_P2, expw, expb, ws + O_HIDA);
    final_kernel<<<320, 256, 0, stream>>>(ws + O_HIDA, outw, outb, out);
}